// Round 1
// baseline (176.305 us; speedup 1.0000x reference)
//
#include <hip/hip_runtime.h>
#include <stdint.h>

typedef __attribute__((ext_vector_type(8))) short short8;
typedef __attribute__((ext_vector_type(4))) short short4v;
typedef __attribute__((ext_vector_type(4))) float float4v;
typedef __attribute__((ext_vector_type(16))) float float16v;
typedef __attribute__((ext_vector_type(4))) uint32_t uint4v;

__device__ __forceinline__ short f2bf(float f) {
    union { float f; uint32_t u; } v; v.f = f;
    uint32_t u = v.u;
    uint32_t r = (u + 0x7fffu + ((u >> 16) & 1u)) >> 16;
    return (short)r;
}

// packed 2x fp32 -> 2x bf16 in one dword (low = first arg)
#if __has_builtin(__builtin_amdgcn_cvt_pk_bf16_f32)
typedef __bf16 bf16x2_t __attribute__((ext_vector_type(2)));
__device__ __forceinline__ uint32_t cvt_pk2(float a, float b) {
    union { bf16x2_t v; uint32_t u; } c;
    c.v = __builtin_amdgcn_cvt_pk_bf16_f32(a, b);
    return c.u;
}
#else
__device__ __forceinline__ uint32_t cvt_pk2(float a, float b) {
    union { float f; uint32_t u; } x, y; x.f = a; y.f = b;
    return ((x.u + 0x8000u) >> 16) | ((y.u + 0x8000u) & 0xFFFF0000u);
}
#endif

// ---------------- merged weight transpose-convert ----------------
// Done ONCE as its own dispatch: r12 proved fusing this into the GEMM K-loop
// re-converts W per m-block (128x redundant) and costs ~9 us net.

__global__ __launch_bounds__(256) void cvtW_kernel(const float* __restrict__ wqkv,
                                                   const float* __restrict__ wproj,
                                                   short* __restrict__ outq,
                                                   short* __restrict__ outp) {
    int idx = blockIdx.x * 256 + threadIdx.x;
    if (idx < 196608) {
        int n = idx >> 8, k = idx & 255;
        outq[idx] = f2bf(wqkv[k * 768 + n]);
    } else {
        int i = idx - 196608;
        int n = i >> 8, k = i & 255;
        outp[i] = f2bf(wproj[k * 256 + n]);
    }
}

// ---------------- GEMM (r5 structure — best measured): 64x64 tile ----------------
// MODE 0: A fp32 (x), bf16-converted during LDS staging; outputs Q/K/V
//         (B,H,N,D), Q pre-scaled by log2(e).  MODE 1: A bf16; fp32 out.

template<int MODE>
__global__ __launch_bounds__(256) void gemm_kernel(
    const void* __restrict__ Ap, const short* __restrict__ Bt,
    const float* __restrict__ bias,
    short* __restrict__ outQ, short* __restrict__ outK, short* __restrict__ outV,
    float* __restrict__ outP)
{
    const int K = 256;
    int m0 = blockIdx.x * 64;
    int n0 = blockIdx.y * 64;
    int tid = threadIdx.x;
    int wave = tid >> 6, lane = tid & 63, quad = lane >> 4, lc = lane & 15;

    __shared__ __align__(16) short As[64 * 48];
    __shared__ __align__(16) short Bs[64 * 48];

    float4v acc[4];
    #pragma unroll
    for (int t = 0; t < 4; ++t) acc[t] = (float4v){0.f, 0.f, 0.f, 0.f};

    int srow = tid >> 2, sseg = tid & 3;

    for (int c = 0; c < K; c += 32) {
        __syncthreads();
        if (MODE == 0) {
            const float* src = (const float*)Ap + (size_t)(m0 + srow) * K + c + sseg * 8;
            float4 f0 = *(const float4*)src;
            float4 f1 = *(const float4*)(src + 4);
            uint4v u; u.x = cvt_pk2(f0.x, f0.y); u.y = cvt_pk2(f0.z, f0.w);
            u.z = cvt_pk2(f1.x, f1.y); u.w = cvt_pk2(f1.z, f1.w);
            *(uint4v*)(&As[srow * 48 + sseg * 8]) = u;
        } else {
            *(short8*)(&As[srow * 48 + sseg * 8]) =
                *(const short8*)((const short*)Ap + (size_t)(m0 + srow) * K + c + sseg * 8);
        }
        *(short8*)(&Bs[srow * 48 + sseg * 8]) =
            *(const short8*)(Bt + (size_t)(n0 + srow) * K + c + sseg * 8);
        __syncthreads();

        short8 af = *(short8*)(&As[(wave * 16 + lc) * 48 + quad * 8]);
        #pragma unroll
        for (int t = 0; t < 4; ++t) {
            short8 bf = *(short8*)(&Bs[(t * 16 + lc) * 48 + quad * 8]);
            acc[t] = __builtin_amdgcn_mfma_f32_16x16x32_bf16(af, bf, acc[t], 0, 0, 0);
        }
    }

    #pragma unroll
    for (int t = 0; t < 4; ++t) {
        int cg = n0 + t * 16 + lc;
        float bv = bias[cg];
        #pragma unroll
        for (int r = 0; r < 4; ++r) {
            int rg = m0 + wave * 16 + quad * 4 + r;
            float val = acc[t][r] + bv;
            if (MODE == 0) {
                int sq = cg >> 8, rem = cg & 255, h = rem >> 4, d = rem & 15;
                int b = rg >> 11, n = rg & 2047;
                if (sq == 0) val *= 1.4426950408889634f;  // fold log2(e) into Q
                short* dst = (sq == 0) ? outQ : ((sq == 1) ? outK : outV);
                dst[((((size_t)b * 16 + h) * 2048 + n) << 4) + d] = f2bf(val);
            } else {
                outP[(size_t)rg * 256 + cg] = val;
            }
        }
    }
}

// ---------------- flash attention (r13: 2-way key-split, 8 waves) ----------------
// grid: (N/128, B*H), 512 threads (8 waves).  Waves 0-3 handle keys 0..1023,
// waves 4-7 handle keys 1024..2047, for the SAME 128 q rows (wave&3 selects the
// 32-row q slice).  No running max exists (pure exp2 + ones-row L), so partials
// combine by simple addition through LDS in the epilogue — no extra HBM traffic.
// Doubles resident waves: 4 -> 8 per SIMD (VGPR<=64 via launch_bounds(512,8)).
//
// Vt is padded to 32 rows per buffer: row 16 = bf16(1.0), rows 17..31 = 0,
// written ONCE at kernel start.  The per-MFMA vf operand is then a single
// unconditional ds_read_b128 (removes the divergent 3-way select of r9).

__global__ __launch_bounds__(512, 8) void attn_kernel(
    const short* __restrict__ Q, const short* __restrict__ Kp, const short* __restrict__ V,
    short* __restrict__ Out)
{
    const int NH = 1024;               // keys per wave-group
    int bh = blockIdx.y;
    int b = bh >> 4, h = bh & 15;
    int tid = threadIdx.x;
    int wave = tid >> 6, lane = tid & 63;
    int m = lane & 31, hi = lane >> 5;
    int grp = wave >> 2;               // 0: keys 0..1023, 1: keys 1024..2047
    int koff = grp << 10;
    int qbase = blockIdx.x * 128 + (wave & 3) * 32;

    const short* Qh = Q + (size_t)bh * 2048 * 16;
    const short* Kh = Kp + (size_t)bh * 2048 * 16;
    const short* Vh = V + (size_t)bh * 2048 * 16;

    // two buffers (one per key-group); rows 0-15 = V^T, row 16 = ones, 17-31 = 0
    __shared__ __align__(16) short Vt[2][32][264];

    // one-time init of the static padding rows (16..31) of both buffers
    for (int idx = tid; idx < 2 * 16 * 264; idx += 512) {
        int buf = idx / (16 * 264);
        int rem = idx - buf * (16 * 264);
        int row = 16 + rem / 264;
        int col = rem - (row - 16) * 264;
        Vt[buf][row][col] = (row == 16) ? (short)0x3F80 : (short)0;
    }

    short8 qf = *(const short8*)(Qh + (size_t)(qbase + m) * 16 + hi * 8);

    float16v Oacc, zf;
    #pragma unroll
    for (int j = 0; j < 16; ++j) { Oacc[j] = 0.f; zf[j] = 0.f; }

    // staging mapping: 256 threads per group stage that group's 256-key chunk
    int t8 = tid & 255;
    int sd = t8 & 15, sa = t8 >> 4;
    int kb = ((sa & 1) << 3) | (((sa >> 1) & 1) << 2) | ((sa >> 2) << 4);

    // ---- V staging prefetch (chunk 0 of this group's range) ----
    short4v vpack[4];
    #pragma unroll
    for (int cc = 0; cc < 4; ++cc) {
        const short* vp = Vh + (size_t)(koff + cc * 64 + kb) * 16 + sd;
        vpack[cc].x = vp[0]; vpack[cc].y = vp[16];
        vpack[cc].z = vp[32]; vpack[cc].w = vp[48];
    }

    // ---- kf prefetch (it 0 of this group's range) ----
    short8 kf1 = *(const short8*)(Kh + (size_t)(koff + m) * 16 + hi * 8);
    short8 kf2 = *(const short8*)(Kh + (size_t)(koff + 32 + m) * 16 + hi * 8);

    for (int sc = 0; sc < NH; sc += 256) {
        __syncthreads();
        #pragma unroll
        for (int cc = 0; cc < 4; ++cc)
            *(short4v*)(&Vt[grp][sd][cc * 64 + sa * 4]) = vpack[cc];
        if (sc + 256 < NH) {   // V prefetch for next chunk — in flight across barrier
            #pragma unroll
            for (int cc = 0; cc < 4; ++cc) {
                const short* vp = Vh + (size_t)(koff + sc + 256 + cc * 64 + kb) * 16 + sd;
                vpack[cc].x = vp[0]; vpack[cc].y = vp[16];
                vpack[cc].z = vp[32]; vpack[cc].w = vp[48];
            }
        }
        __syncthreads();

        #pragma unroll
        for (int it = 0; it < 4; ++it) {
            int c = sc + it * 64;
            int cn = (c + 64) & (NH - 1);   // next-it key base within group (wraps)

            float16v S1 = __builtin_amdgcn_mfma_f32_32x32x16_bf16(kf1, qf, zf, 0, 0, 0);
            float16v S2 = __builtin_amdgcn_mfma_f32_32x32x16_bf16(kf2, qf, zf, 0, 0, 0);

            // prefetch next it's K fragments; latency hidden by exp/pack/PV below
            kf1 = *(const short8*)(Kh + (size_t)(koff + cn + m) * 16 + hi * 8);
            kf2 = *(const short8*)(Kh + (size_t)(koff + cn + 32 + m) * 16 + hi * 8);

            union { uint4v u; short8 s; } pA, pB, pC, pD;
            pA.u = (uint4v){
                cvt_pk2(__builtin_amdgcn_exp2f(S1[0]), __builtin_amdgcn_exp2f(S1[1])),
                cvt_pk2(__builtin_amdgcn_exp2f(S1[2]), __builtin_amdgcn_exp2f(S1[3])),
                cvt_pk2(__builtin_amdgcn_exp2f(S1[4]), __builtin_amdgcn_exp2f(S1[5])),
                cvt_pk2(__builtin_amdgcn_exp2f(S1[6]), __builtin_amdgcn_exp2f(S1[7]))};
            pB.u = (uint4v){
                cvt_pk2(__builtin_amdgcn_exp2f(S1[8]),  __builtin_amdgcn_exp2f(S1[9])),
                cvt_pk2(__builtin_amdgcn_exp2f(S1[10]), __builtin_amdgcn_exp2f(S1[11])),
                cvt_pk2(__builtin_amdgcn_exp2f(S1[12]), __builtin_amdgcn_exp2f(S1[13])),
                cvt_pk2(__builtin_amdgcn_exp2f(S1[14]), __builtin_amdgcn_exp2f(S1[15]))};
            pC.u = (uint4v){
                cvt_pk2(__builtin_amdgcn_exp2f(S2[0]), __builtin_amdgcn_exp2f(S2[1])),
                cvt_pk2(__builtin_amdgcn_exp2f(S2[2]), __builtin_amdgcn_exp2f(S2[3])),
                cvt_pk2(__builtin_amdgcn_exp2f(S2[4]), __builtin_amdgcn_exp2f(S2[5])),
                cvt_pk2(__builtin_amdgcn_exp2f(S2[6]), __builtin_amdgcn_exp2f(S2[7]))};
            pD.u = (uint4v){
                cvt_pk2(__builtin_amdgcn_exp2f(S2[8]),  __builtin_amdgcn_exp2f(S2[9])),
                cvt_pk2(__builtin_amdgcn_exp2f(S2[10]), __builtin_amdgcn_exp2f(S2[11])),
                cvt_pk2(__builtin_amdgcn_exp2f(S2[12]), __builtin_amdgcn_exp2f(S2[13])),
                cvt_pk2(__builtin_amdgcn_exp2f(S2[14]), __builtin_amdgcn_exp2f(S2[15]))};

            #pragma unroll
            for (int p = 0; p < 4; ++p) {
                short8 vf = *(short8*)(&Vt[grp][m][it * 64 + p * 16 + hi * 8]);
                short8 pf = (p == 0) ? pA.s : (p == 1) ? pB.s : (p == 2) ? pC.s : pD.s;
                Oacc = __builtin_amdgcn_mfma_f32_32x32x16_bf16(vf, pf, Oacc, 0, 0, 0);
            }
        }
    }

    // ---- combine the two key-halves through LDS (reuse Vt) ----
    // Useful partial state per lane: Oacc[0..7] = O rows (d), Oacc[8] = L (hi==0)
    // (rows 17..31 of the extended V^T are zero, so Oacc[9..15] contribute nothing).
    __syncthreads();
    float* cb = (float*)&Vt[0][0][0];
    if (wave >= 4) {
        int base = ((wave - 4) * 64 + lane) * 12;
        *(float4v*)(cb + base)     = (float4v){Oacc[0], Oacc[1], Oacc[2], Oacc[3]};
        *(float4v*)(cb + base + 4) = (float4v){Oacc[4], Oacc[5], Oacc[6], Oacc[7]};
        cb[base + 8] = Oacc[8];
    }
    __syncthreads();
    if (wave < 4) {
        int base = (wave * 64 + lane) * 12;
        float4v p0 = *(float4v*)(cb + base);
        float4v p1 = *(float4v*)(cb + base + 4);
        float Lp = cb[base + 8];
        Oacc[0] += p0[0]; Oacc[1] += p0[1]; Oacc[2] += p0[2]; Oacc[3] += p0[3];
        Oacc[4] += p1[0]; Oacc[5] += p1[1]; Oacc[6] += p1[2]; Oacc[7] += p1[3];
        Oacc[8] += Lp;

        // epilogue: L = row 16 (reg 8, hi==0 lanes); O[q][d] = Oacc_d / L
        float Lq = __shfl(Oacc[8], m, 64);
        float inv = 1.0f / Lq;
        uint32_t o0 = cvt_pk2(Oacc[0] * inv, Oacc[1] * inv);
        uint32_t o1 = cvt_pk2(Oacc[2] * inv, Oacc[3] * inv);
        uint32_t o2 = cvt_pk2(Oacc[4] * inv, Oacc[5] * inv);
        uint32_t o3 = cvt_pk2(Oacc[6] * inv, Oacc[7] * inv);
        short* row = Out + ((size_t)(b * 2048 + qbase + m)) * 256 + h * 16;
        uint2 w0; w0.x = o0; w0.y = o1;
        uint2 w1; w1.x = o2; w1.y = o3;
        *(uint2*)(row + hi * 4) = w0;
        *(uint2*)(row + 8 + hi * 4) = w1;
    }
}

// ---------------- launcher ----------------

extern "C" void kernel_launch(void* const* d_in, const int* in_sizes, int n_in,
                              void* d_out, int out_size, void* d_ws, size_t ws_size,
                              hipStream_t stream) {
    const float* x      = (const float*)d_in[0];
    const float* w_qkv  = (const float*)d_in[1];
    const float* b_qkv  = (const float*)d_in[2];
    const float* w_proj = (const float*)d_in[3];
    const float* b_proj = (const float*)d_in[4];
    float* out = (float*)d_out;

    short* wqkvT  = (short*)d_ws;          // 768*256
    short* wprojT = wqkvT + 196608;        // 256*256
    short* Qb     = wprojT + 65536;        // (B*H, N, D) bf16
    short* Kb     = Qb + 2097152;
    short* Vb     = Kb + 2097152;
    short* Ab     = Vb + 2097152;          // attention output (B,N,C) bf16

    cvtW_kernel<<<1024, 256, 0, stream>>>(w_qkv, w_proj, wqkvT, wprojT);

    gemm_kernel<0><<<dim3(128, 12), 256, 0, stream>>>(x, wqkvT, b_qkv, Qb, Kb, Vb, nullptr);

    attn_kernel<<<dim3(16, 64), 512, 0, stream>>>(Qb, Kb, Vb, Ab);

    gemm_kernel<1><<<dim3(128, 4), 256, 0, stream>>>(Ab, wprojT, b_proj,
                                                     nullptr, nullptr, nullptr, out);
}

// Round 2
// 143.202 us; speedup vs baseline: 1.2312x; 1.2312x over previous
//
#include <hip/hip_runtime.h>
#include <stdint.h>

typedef __attribute__((ext_vector_type(8))) short short8;
typedef __attribute__((ext_vector_type(4))) short short4v;
typedef __attribute__((ext_vector_type(4))) float float4v;
typedef __attribute__((ext_vector_type(16))) float float16v;
typedef __attribute__((ext_vector_type(4))) uint32_t uint4v;

__device__ __forceinline__ short f2bf(float f) {
    union { float f; uint32_t u; } v; v.f = f;
    uint32_t u = v.u;
    uint32_t r = (u + 0x7fffu + ((u >> 16) & 1u)) >> 16;
    return (short)r;
}

// packed 2x fp32 -> 2x bf16 in one dword (low = first arg)
#if __has_builtin(__builtin_amdgcn_cvt_pk_bf16_f32)
typedef __bf16 bf16x2_t __attribute__((ext_vector_type(2)));
__device__ __forceinline__ uint32_t cvt_pk2(float a, float b) {
    union { bf16x2_t v; uint32_t u; } c;
    c.v = __builtin_amdgcn_cvt_pk_bf16_f32(a, b);
    return c.u;
}
#else
__device__ __forceinline__ uint32_t cvt_pk2(float a, float b) {
    union { float f; uint32_t u; } x, y; x.f = a; y.f = b;
    return ((x.u + 0x8000u) >> 16) | ((y.u + 0x8000u) & 0xFFFF0000u);
}
#endif

// ---------------- merged weight transpose-convert ----------------

__global__ __launch_bounds__(256) void cvtW_kernel(const float* __restrict__ wqkv,
                                                   const float* __restrict__ wproj,
                                                   short* __restrict__ outq,
                                                   short* __restrict__ outp) {
    int idx = blockIdx.x * 256 + threadIdx.x;
    if (idx < 196608) {
        int n = idx >> 8, k = idx & 255;
        outq[idx] = f2bf(wqkv[k * 768 + n]);
    } else {
        int i = idx - 196608;
        int n = i >> 8, k = i & 255;
        outp[i] = f2bf(wproj[k * 256 + n]);
    }
}

// ---------------- GEMM (r5 structure — best measured): 64x64 tile ----------------
// MODE 0: A fp32 (x), bf16-converted during LDS staging; outputs Q/K/V
//         (B,H,N,D), Q pre-scaled by log2(e).  MODE 1: A bf16; fp32 out.

template<int MODE>
__global__ __launch_bounds__(256) void gemm_kernel(
    const void* __restrict__ Ap, const short* __restrict__ Bt,
    const float* __restrict__ bias,
    short* __restrict__ outQ, short* __restrict__ outK, short* __restrict__ outV,
    float* __restrict__ outP)
{
    const int K = 256;
    int m0 = blockIdx.x * 64;
    int n0 = blockIdx.y * 64;
    int tid = threadIdx.x;
    int wave = tid >> 6, lane = tid & 63, quad = lane >> 4, lc = lane & 15;

    __shared__ __align__(16) short As[64 * 48];
    __shared__ __align__(16) short Bs[64 * 48];

    float4v acc[4];
    #pragma unroll
    for (int t = 0; t < 4; ++t) acc[t] = (float4v){0.f, 0.f, 0.f, 0.f};

    int srow = tid >> 2, sseg = tid & 3;

    for (int c = 0; c < K; c += 32) {
        __syncthreads();
        if (MODE == 0) {
            const float* src = (const float*)Ap + (size_t)(m0 + srow) * K + c + sseg * 8;
            float4 f0 = *(const float4*)src;
            float4 f1 = *(const float4*)(src + 4);
            uint4v u; u.x = cvt_pk2(f0.x, f0.y); u.y = cvt_pk2(f0.z, f0.w);
            u.z = cvt_pk2(f1.x, f1.y); u.w = cvt_pk2(f1.z, f1.w);
            *(uint4v*)(&As[srow * 48 + sseg * 8]) = u;
        } else {
            *(short8*)(&As[srow * 48 + sseg * 8]) =
                *(const short8*)((const short*)Ap + (size_t)(m0 + srow) * K + c + sseg * 8);
        }
        *(short8*)(&Bs[srow * 48 + sseg * 8]) =
            *(const short8*)(Bt + (size_t)(n0 + srow) * K + c + sseg * 8);
        __syncthreads();

        short8 af = *(short8*)(&As[(wave * 16 + lc) * 48 + quad * 8]);
        #pragma unroll
        for (int t = 0; t < 4; ++t) {
            short8 bf = *(short8*)(&Bs[(t * 16 + lc) * 48 + quad * 8]);
            acc[t] = __builtin_amdgcn_mfma_f32_16x16x32_bf16(af, bf, acc[t], 0, 0, 0);
        }
    }

    #pragma unroll
    for (int t = 0; t < 4; ++t) {
        int cg = n0 + t * 16 + lc;
        float bv = bias[cg];
        #pragma unroll
        for (int r = 0; r < 4; ++r) {
            int rg = m0 + wave * 16 + quad * 4 + r;
            float val = acc[t][r] + bv;
            if (MODE == 0) {
                int sq = cg >> 8, rem = cg & 255, h = rem >> 4, d = rem & 15;
                int b = rg >> 11, n = rg & 2047;
                if (sq == 0) val *= 1.4426950408889634f;  // fold log2(e) into Q
                short* dst = (sq == 0) ? outQ : ((sq == 1) ? outK : outV);
                dst[((((size_t)b * 16 + h) * 2048 + n) << 4) + d] = f2bf(val);
            } else {
                outP[(size_t)rg * 256 + cg] = val;
            }
        }
    }
}

// ---------------- flash attention (r14: split-K across BLOCKS) ----------------
// r13 post-mortem: in-block key-split with launch_bounds(512,8) forced VGPR 64->32,
// spilling ~350 MB of scratch (WRITE_SIZE 218 MB).  The occupancy theory held
// (31->60%); the register squeeze was the failure.  r14 keeps the proven r9
// 256-thread / 64-VGPR structure VERBATIM in the main loop and doubles waves by
// grid z=2: block z handles keys z*1024..+1024 and writes fp32 partial O + L;
// combine_kernel sums the two halves and normalizes (exact re-association —
// no running max exists in this formulation).
//
// Kept from r13 (independent, register-neutral): Vt padded to 32 rows, row 16 =
// bf16(1.0), rows 17..31 = 0, written once => per-MFMA V operand is a single
// unconditional ds_read_b128 (kills the divergent 3-way select; frees the
// ones/zeros registers too).  Staging only writes rows 0..15.

__global__ __launch_bounds__(256) void attn_kernel(
    const short* __restrict__ Q, const short* __restrict__ Kp, const short* __restrict__ V,
    float* __restrict__ Pout, float* __restrict__ Lout)
{
    const int NH = 1024;               // keys handled by this block
    int bh = blockIdx.y;
    int split = blockIdx.z;
    int tid = threadIdx.x;
    int wave = tid >> 6, lane = tid & 63;
    int m = lane & 31, hi = lane >> 5;
    int qbase = blockIdx.x * 128 + wave * 32;

    const short* Qh = Q + (size_t)bh * 2048 * 16;
    const short* Kh = Kp + ((size_t)bh * 2048 + (split << 10)) * 16;
    const short* Vh = V + ((size_t)bh * 2048 + (split << 10)) * 16;

    // rows 0-15 = V^T (staged per chunk), row 16 = ones, rows 17-31 = 0 (static)
    __shared__ __align__(16) short Vt[32][264];

    for (int idx = tid; idx < 16 * 264; idx += 256) {
        int row = 16 + idx / 264;
        int col = idx - (row - 16) * 264;
        Vt[row][col] = (row == 16) ? (short)0x3F80 : (short)0;
    }

    short8 qf = *(const short8*)(Qh + (size_t)(qbase + m) * 16 + hi * 8);

    float16v Oacc, zf;
    #pragma unroll
    for (int j = 0; j < 16; ++j) { Oacc[j] = 0.f; zf[j] = 0.f; }

    int sd = tid & 15, sa = tid >> 4;
    int kb = ((sa & 1) << 3) | (((sa >> 1) & 1) << 2) | ((sa >> 2) << 4);

    // ---- V staging prefetch (chunk 0) ----
    short4v vpack[4];
    #pragma unroll
    for (int cc = 0; cc < 4; ++cc) {
        const short* vp = Vh + (size_t)(cc * 64 + kb) * 16 + sd;
        vpack[cc].x = vp[0]; vpack[cc].y = vp[16];
        vpack[cc].z = vp[32]; vpack[cc].w = vp[48];
    }

    // ---- kf prefetch (it 0) ----
    short8 kf1 = *(const short8*)(Kh + (size_t)m * 16 + hi * 8);
    short8 kf2 = *(const short8*)(Kh + (size_t)(32 + m) * 16 + hi * 8);

    for (int sc = 0; sc < NH; sc += 256) {
        __syncthreads();
        #pragma unroll
        for (int cc = 0; cc < 4; ++cc)
            *(short4v*)(&Vt[sd][cc * 64 + sa * 4]) = vpack[cc];
        if (sc + 256 < NH) {   // V prefetch for next chunk — in flight across barrier
            #pragma unroll
            for (int cc = 0; cc < 4; ++cc) {
                const short* vp = Vh + (size_t)(sc + 256 + cc * 64 + kb) * 16 + sd;
                vpack[cc].x = vp[0]; vpack[cc].y = vp[16];
                vpack[cc].z = vp[32]; vpack[cc].w = vp[48];
            }
        }
        __syncthreads();

        #pragma unroll
        for (int it = 0; it < 4; ++it) {
            int c = sc + it * 64;
            int cn = (c + 64) & (NH - 1);   // next-it key base (wraps harmlessly)

            float16v S1 = __builtin_amdgcn_mfma_f32_32x32x16_bf16(kf1, qf, zf, 0, 0, 0);
            float16v S2 = __builtin_amdgcn_mfma_f32_32x32x16_bf16(kf2, qf, zf, 0, 0, 0);

            // prefetch next it's K fragments; latency hidden by exp/pack/PV below
            kf1 = *(const short8*)(Kh + (size_t)(cn + m) * 16 + hi * 8);
            kf2 = *(const short8*)(Kh + (size_t)(cn + 32 + m) * 16 + hi * 8);

            union { uint4v u; short8 s; } pA, pB, pC, pD;
            pA.u = (uint4v){
                cvt_pk2(__builtin_amdgcn_exp2f(S1[0]), __builtin_amdgcn_exp2f(S1[1])),
                cvt_pk2(__builtin_amdgcn_exp2f(S1[2]), __builtin_amdgcn_exp2f(S1[3])),
                cvt_pk2(__builtin_amdgcn_exp2f(S1[4]), __builtin_amdgcn_exp2f(S1[5])),
                cvt_pk2(__builtin_amdgcn_exp2f(S1[6]), __builtin_amdgcn_exp2f(S1[7]))};
            pB.u = (uint4v){
                cvt_pk2(__builtin_amdgcn_exp2f(S1[8]),  __builtin_amdgcn_exp2f(S1[9])),
                cvt_pk2(__builtin_amdgcn_exp2f(S1[10]), __builtin_amdgcn_exp2f(S1[11])),
                cvt_pk2(__builtin_amdgcn_exp2f(S1[12]), __builtin_amdgcn_exp2f(S1[13])),
                cvt_pk2(__builtin_amdgcn_exp2f(S1[14]), __builtin_amdgcn_exp2f(S1[15]))};
            pC.u = (uint4v){
                cvt_pk2(__builtin_amdgcn_exp2f(S2[0]), __builtin_amdgcn_exp2f(S2[1])),
                cvt_pk2(__builtin_amdgcn_exp2f(S2[2]), __builtin_amdgcn_exp2f(S2[3])),
                cvt_pk2(__builtin_amdgcn_exp2f(S2[4]), __builtin_amdgcn_exp2f(S2[5])),
                cvt_pk2(__builtin_amdgcn_exp2f(S2[6]), __builtin_amdgcn_exp2f(S2[7]))};
            pD.u = (uint4v){
                cvt_pk2(__builtin_amdgcn_exp2f(S2[8]),  __builtin_amdgcn_exp2f(S2[9])),
                cvt_pk2(__builtin_amdgcn_exp2f(S2[10]), __builtin_amdgcn_exp2f(S2[11])),
                cvt_pk2(__builtin_amdgcn_exp2f(S2[12]), __builtin_amdgcn_exp2f(S2[13])),
                cvt_pk2(__builtin_amdgcn_exp2f(S2[14]), __builtin_amdgcn_exp2f(S2[15]))};

            #pragma unroll
            for (int p = 0; p < 4; ++p) {
                short8 vf = *(short8*)(&Vt[m][it * 64 + p * 16 + hi * 8]);
                short8 pf = (p == 0) ? pA.s : (p == 1) ? pB.s : (p == 2) ? pC.s : pD.s;
                Oacc = __builtin_amdgcn_mfma_f32_32x32x16_bf16(vf, pf, Oacc, 0, 0, 0);
            }
        }
    }

    // ---- epilogue: write fp32 partials ----
    // lane (m,hi) holds O[q=qbase+m][d] for d = hi*4+0..3 (Oacc 0..3) and
    // d = 8+hi*4+0..3 (Oacc 4..7); L = Oacc[8] on hi==0 lanes (ones row 16).
    size_t qi = (size_t)bh * 2048 + qbase + m;
    float* pb = Pout + ((size_t)split * 131072 + qi) * 16;
    *(float4v*)(pb + hi * 4)     = (float4v){Oacc[0], Oacc[1], Oacc[2], Oacc[3]};
    *(float4v*)(pb + 8 + hi * 4) = (float4v){Oacc[4], Oacc[5], Oacc[6], Oacc[7]};
    if (hi == 0) Lout[(size_t)split * 131072 + qi] = Oacc[8];
}

// ---------------- split-K combine: Ab = (O0+O1)/(L0+L1), bf16 ----------------
// idx = ((b*2048+n)*16 + h): h fastest => wave writes 2 KB contiguous to Ab.
// Per-thread reads are one full 64 B line per split.

__global__ __launch_bounds__(256) void combine_kernel(const float* __restrict__ P,
                                                      const float* __restrict__ Lb,
                                                      short* __restrict__ Ab) {
    int idx = blockIdx.x * 256 + threadIdx.x;   // 131072 total
    int h = idx & 15;
    int bn = idx >> 4;                          // b*2048 + n
    int b = bn >> 11;
    size_t qi = ((size_t)(b * 16 + h)) * 2048 + (bn & 2047);
    const float* p0 = P + qi * 16;
    const float* p1 = P + (qi + 131072) * 16;
    float inv = 1.0f / (Lb[qi] + Lb[qi + 131072]);
    float4v a0 = *(const float4v*)(p0);
    float4v a1 = *(const float4v*)(p0 + 4);
    float4v a2 = *(const float4v*)(p0 + 8);
    float4v a3 = *(const float4v*)(p0 + 12);
    float4v c0 = *(const float4v*)(p1);
    float4v c1 = *(const float4v*)(p1 + 4);
    float4v c2 = *(const float4v*)(p1 + 8);
    float4v c3 = *(const float4v*)(p1 + 12);
    uint4v o0, o1;
    o0.x = cvt_pk2((a0[0] + c0[0]) * inv, (a0[1] + c0[1]) * inv);
    o0.y = cvt_pk2((a0[2] + c0[2]) * inv, (a0[3] + c0[3]) * inv);
    o0.z = cvt_pk2((a1[0] + c1[0]) * inv, (a1[1] + c1[1]) * inv);
    o0.w = cvt_pk2((a1[2] + c1[2]) * inv, (a1[3] + c1[3]) * inv);
    o1.x = cvt_pk2((a2[0] + c2[0]) * inv, (a2[1] + c2[1]) * inv);
    o1.y = cvt_pk2((a2[2] + c2[2]) * inv, (a2[3] + c2[3]) * inv);
    o1.z = cvt_pk2((a3[0] + c3[0]) * inv, (a3[1] + c3[1]) * inv);
    o1.w = cvt_pk2((a3[2] + c3[2]) * inv, (a3[3] + c3[3]) * inv);
    short* row = Ab + (size_t)bn * 256 + h * 16;
    *(uint4v*)(row)     = o0;
    *(uint4v*)(row + 8) = o1;
}

// ---------------- launcher ----------------

extern "C" void kernel_launch(void* const* d_in, const int* in_sizes, int n_in,
                              void* d_out, int out_size, void* d_ws, size_t ws_size,
                              hipStream_t stream) {
    const float* x      = (const float*)d_in[0];
    const float* w_qkv  = (const float*)d_in[1];
    const float* b_qkv  = (const float*)d_in[2];
    const float* w_proj = (const float*)d_in[3];
    const float* b_proj = (const float*)d_in[4];
    float* out = (float*)d_out;

    short* wqkvT  = (short*)d_ws;          // 768*256
    short* wprojT = wqkvT + 196608;        // 256*256
    short* Qb     = wprojT + 65536;        // (B*H, N, D) bf16
    short* Kb     = Qb + 2097152;
    short* Vb     = Kb + 2097152;
    short* Ab     = Vb + 2097152;          // attention output (B,N,C) bf16
    float* Pp     = (float*)(Ab + 2097152);  // partial O: [2][BH*N][16] fp32
    float* Lp     = Pp + 4194304;            // partial L: [2][BH*N] fp32

    cvtW_kernel<<<1024, 256, 0, stream>>>(w_qkv, w_proj, wqkvT, wprojT);

    gemm_kernel<0><<<dim3(128, 12), 256, 0, stream>>>(x, wqkvT, b_qkv, Qb, Kb, Vb, nullptr);

    attn_kernel<<<dim3(16, 64, 2), 256, 0, stream>>>(Qb, Kb, Vb, Pp, Lp);

    combine_kernel<<<512, 256, 0, stream>>>(Pp, Lp, Ab);

    gemm_kernel<1><<<dim3(128, 4), 256, 0, stream>>>(Ab, wprojT, b_proj,
                                                     nullptr, nullptr, nullptr, out);
}

// Round 3
// 136.215 us; speedup vs baseline: 1.2943x; 1.0513x over previous
//
#include <hip/hip_runtime.h>
#include <stdint.h>

typedef __attribute__((ext_vector_type(8))) short short8;
typedef __attribute__((ext_vector_type(4))) short short4v;
typedef __attribute__((ext_vector_type(4))) float float4v;
typedef __attribute__((ext_vector_type(16))) float float16v;
typedef __attribute__((ext_vector_type(4))) uint32_t uint4v;

__device__ __forceinline__ short f2bf(float f) {
    union { float f; uint32_t u; } v; v.f = f;
    uint32_t u = v.u;
    uint32_t r = (u + 0x7fffu + ((u >> 16) & 1u)) >> 16;
    return (short)r;
}

#if __has_builtin(__builtin_amdgcn_cvt_pk_bf16_f32)
typedef __bf16 bf16x2_t __attribute__((ext_vector_type(2)));
__device__ __forceinline__ uint32_t cvt_pk2(float a, float b) {
    union { bf16x2_t v; uint32_t u; } c;
    c.v = __builtin_amdgcn_cvt_pk_bf16_f32(a, b);
    return c.u;
}
#else
__device__ __forceinline__ uint32_t cvt_pk2(float a, float b) {
    union { float f; uint32_t u; } x, y; x.f = a; y.f = b;
    return ((x.u + 0x8000u) >> 16) | ((y.u + 0x8000u) & 0xFFFF0000u);
}
#endif

// async 16B global -> LDS (DMA write: no LDS bank conflicts on the write side).
// LDS dest is wave-uniform base + lane*16 — lane mapping below guarantees that.
__device__ __forceinline__ void async_ld16(short* lds, const short* g) {
    __builtin_amdgcn_global_load_lds(
        (const __attribute__((address_space(1))) void*)g,
        (__attribute__((address_space(3))) void*)lds, 16, 0, 0);
}

// ---------------- conversions: weights (transposed) + x -> bf16 ----------------
// gid < 262144: vector-convert 8 x-floats each (x: 4*2048*256 = 2,097,152 fp32).
// else: scalar transpose-convert of wqkv/wproj (as before).

__global__ __launch_bounds__(256) void cvtW_kernel(const float* __restrict__ wqkv,
                                                   const float* __restrict__ wproj,
                                                   const float* __restrict__ x,
                                                   short* __restrict__ outq,
                                                   short* __restrict__ outp,
                                                   short* __restrict__ xb) {
    int gid = blockIdx.x * 256 + threadIdx.x;
    if (gid < 262144) {
        const float* src = x + (size_t)gid * 8;
        float4 f0 = *(const float4*)src;
        float4 f1 = *(const float4*)(src + 4);
        uint4v u; u.x = cvt_pk2(f0.x, f0.y); u.y = cvt_pk2(f0.z, f0.w);
        u.z = cvt_pk2(f1.x, f1.y); u.w = cvt_pk2(f1.z, f1.w);
        *(uint4v*)(xb + (size_t)gid * 8) = u;
    } else {
        int idx = gid - 262144;
        if (idx < 196608) {
            int n = idx >> 8, k = idx & 255;
            outq[idx] = f2bf(wqkv[k * 768 + n]);
        } else {
            int i = idx - 196608;
            int n = i >> 8, k = i & 255;
            outp[i] = f2bf(wproj[k * 256 + n]);
        }
    }
}

// ---------------- GEMM v2: TM x 128 tile, BK=64, global_load_lds + XOR swizzle ----
// 256 threads = 4 waves in 2x2; wave (wr,wc) owns (TM/2) x 64 of the output.
// LDS linear [row][64] bf16 (128B rows); staging DMA writes lane-linear; the
// bank-spread permutation (col16 ^= row&7) is applied on the GLOBAL source
// (rule: both-sides-or-neither) and re-applied on every ds_read_b128.
// MODE 0 (TM=128): A = xb (bf16), outputs Q/K/V (B,H,N,D) bf16, Q * log2(e).
// MODE 1 (TM=64):  A = Ab (bf16), output fp32 row-major + bias.

template<int TM, int MODE>
__global__ __launch_bounds__(256) void gemm2_kernel(
    const short* __restrict__ A, const short* __restrict__ Bt,
    const float* __restrict__ bias,
    short* __restrict__ outQ, short* __restrict__ outK, short* __restrict__ outV,
    float* __restrict__ outP)
{
    const int K = 256;
    const int MI = TM / 32;               // A-frags per wave
    int tid = threadIdx.x;
    int w = tid >> 6, lane = tid & 63;
    int wr = w >> 1, wc = w & 1;
    int quad = lane >> 4, lc = lane & 15;
    int m0 = blockIdx.x * TM, n0 = blockIdx.y * 128;

    __shared__ __align__(16) short As[TM * 64];
    __shared__ __align__(16) short Bs[128 * 64];

    float4v acc[MI][4];
    #pragma unroll
    for (int i = 0; i < MI; ++i)
        #pragma unroll
        for (int j = 0; j < 4; ++j) acc[i][j] = (float4v){0.f, 0.f, 0.f, 0.f};

    int l8 = lane >> 3, l7 = lane & 7;
    int scol = ((l7 ^ l8) * 8);           // pre-swizzled global col (elements)

    for (int kt = 0; kt < 4; ++kt) {
        int c = kt * 64;
        __syncthreads();                   // prior-iter frag reads complete
        #pragma unroll
        for (int i = 0; i < TM / 32; ++i) {
            int row = i * 32 + w * 8 + l8;     // row&7 == l8
            async_ld16(&As[row * 64 + l7 * 8],
                       A + (size_t)(m0 + row) * K + c + scol);
        }
        #pragma unroll
        for (int i = 0; i < 4; ++i) {
            int row = i * 32 + w * 8 + l8;
            async_ld16(&Bs[row * 64 + l7 * 8],
                       Bt + (size_t)(n0 + row) * K + c + scol);
        }
        __syncthreads();                   // vmcnt(0) drain -> tile visible

        #pragma unroll
        for (int ks = 0; ks < 2; ++ks) {
            short8 af[MI], bf[4];
            #pragma unroll
            for (int i = 0; i < MI; ++i) {
                int r = wr * (TM / 2) + i * 16 + lc;
                af[i] = *(short8*)(&As[r * 64 + (((ks * 4 + quad) ^ (r & 7)) * 8)]);
            }
            #pragma unroll
            for (int j = 0; j < 4; ++j) {
                int r = wc * 64 + j * 16 + lc;
                bf[j] = *(short8*)(&Bs[r * 64 + (((ks * 4 + quad) ^ (r & 7)) * 8)]);
            }
            #pragma unroll
            for (int i = 0; i < MI; ++i)
                #pragma unroll
                for (int j = 0; j < 4; ++j)
                    acc[i][j] = __builtin_amdgcn_mfma_f32_16x16x32_bf16(af[i], bf[j], acc[i][j], 0, 0, 0);
        }
    }

    #pragma unroll
    for (int i = 0; i < MI; ++i) {
        #pragma unroll
        for (int j = 0; j < 4; ++j) {
            int cg = n0 + wc * 64 + j * 16 + lc;
            float bv = bias[cg];
            #pragma unroll
            for (int r = 0; r < 4; ++r) {
                int rg = m0 + wr * (TM / 2) + i * 16 + quad * 4 + r;
                float val = acc[i][j][r] + bv;
                if (MODE == 0) {
                    int sq = cg >> 8, rem = cg & 255, h = rem >> 4, d = rem & 15;
                    int b = rg >> 11, n = rg & 2047;
                    if (sq == 0) val *= 1.4426950408889634f;  // fold log2(e) into Q
                    short* dst = (sq == 0) ? outQ : ((sq == 1) ? outK : outV);
                    dst[((((size_t)b * 16 + h) * 2048 + n) << 4) + d] = f2bf(val);
                } else {
                    outP[(size_t)rg * 256 + cg] = val;
                }
            }
        }
    }
}

// ---------------- flash attention (r15 = r9 structure + padded Vt) ----------------
// Single dispatch again: r14's split-K bought -4us on attn but cost ~14us in
// combine + fp32 partial traffic (total 133->143).  Occupancy is register-capped
// (VGPR+AGPR ~128/wave -> 4 waves/SIMD) regardless of grid — accepted.
// Kept: Vt padded to 32 rows (row 16 = 1.0, 17..31 = 0, written once) so the
// per-MFMA V operand is one unconditional ds_read_b128 (no divergent select).

__global__ __launch_bounds__(256) void attn_kernel(
    const short* __restrict__ Q, const short* __restrict__ Kp, const short* __restrict__ V,
    short* __restrict__ Out)
{
    const int N = 2048;
    int bh = blockIdx.y;
    int b = bh >> 4, h = bh & 15;
    int tid = threadIdx.x;
    int wave = tid >> 6, lane = tid & 63;
    int m = lane & 31, hi = lane >> 5;
    int qbase = blockIdx.x * 128 + wave * 32;

    const short* Qh = Q + (size_t)bh * N * 16;
    const short* Kh = Kp + (size_t)bh * N * 16;
    const short* Vh = V + (size_t)bh * N * 16;

    __shared__ __align__(16) short Vt[32][264];

    for (int idx = tid; idx < 16 * 264; idx += 256) {
        int row = 16 + idx / 264;
        int col = idx - (row - 16) * 264;
        Vt[row][col] = (row == 16) ? (short)0x3F80 : (short)0;
    }

    short8 qf = *(const short8*)(Qh + (size_t)(qbase + m) * 16 + hi * 8);

    float16v Oacc, zf;
    #pragma unroll
    for (int j = 0; j < 16; ++j) { Oacc[j] = 0.f; zf[j] = 0.f; }

    int sd = tid & 15, sa = tid >> 4;
    int kb = ((sa & 1) << 3) | (((sa >> 1) & 1) << 2) | ((sa >> 2) << 4);

    short4v vpack[4];
    #pragma unroll
    for (int cc = 0; cc < 4; ++cc) {
        const short* vp = Vh + (size_t)(cc * 64 + kb) * 16 + sd;
        vpack[cc].x = vp[0]; vpack[cc].y = vp[16];
        vpack[cc].z = vp[32]; vpack[cc].w = vp[48];
    }

    short8 kf1 = *(const short8*)(Kh + (size_t)m * 16 + hi * 8);
    short8 kf2 = *(const short8*)(Kh + (size_t)(32 + m) * 16 + hi * 8);

    for (int sc = 0; sc < N; sc += 256) {
        __syncthreads();
        #pragma unroll
        for (int cc = 0; cc < 4; ++cc)
            *(short4v*)(&Vt[sd][cc * 64 + sa * 4]) = vpack[cc];
        if (sc + 256 < N) {
            #pragma unroll
            for (int cc = 0; cc < 4; ++cc) {
                const short* vp = Vh + (size_t)(sc + 256 + cc * 64 + kb) * 16 + sd;
                vpack[cc].x = vp[0]; vpack[cc].y = vp[16];
                vpack[cc].z = vp[32]; vpack[cc].w = vp[48];
            }
        }
        __syncthreads();

        #pragma unroll
        for (int it = 0; it < 4; ++it) {
            int c = sc + it * 64;
            int cn = (c + 64) & (N - 1);

            float16v S1 = __builtin_amdgcn_mfma_f32_32x32x16_bf16(kf1, qf, zf, 0, 0, 0);
            float16v S2 = __builtin_amdgcn_mfma_f32_32x32x16_bf16(kf2, qf, zf, 0, 0, 0);

            kf1 = *(const short8*)(Kh + (size_t)(cn + m) * 16 + hi * 8);
            kf2 = *(const short8*)(Kh + (size_t)(cn + 32 + m) * 16 + hi * 8);

            union { uint4v u; short8 s; } pA, pB, pC, pD;
            pA.u = (uint4v){
                cvt_pk2(__builtin_amdgcn_exp2f(S1[0]), __builtin_amdgcn_exp2f(S1[1])),
                cvt_pk2(__builtin_amdgcn_exp2f(S1[2]), __builtin_amdgcn_exp2f(S1[3])),
                cvt_pk2(__builtin_amdgcn_exp2f(S1[4]), __builtin_amdgcn_exp2f(S1[5])),
                cvt_pk2(__builtin_amdgcn_exp2f(S1[6]), __builtin_amdgcn_exp2f(S1[7]))};
            pB.u = (uint4v){
                cvt_pk2(__builtin_amdgcn_exp2f(S1[8]),  __builtin_amdgcn_exp2f(S1[9])),
                cvt_pk2(__builtin_amdgcn_exp2f(S1[10]), __builtin_amdgcn_exp2f(S1[11])),
                cvt_pk2(__builtin_amdgcn_exp2f(S1[12]), __builtin_amdgcn_exp2f(S1[13])),
                cvt_pk2(__builtin_amdgcn_exp2f(S1[14]), __builtin_amdgcn_exp2f(S1[15]))};
            pC.u = (uint4v){
                cvt_pk2(__builtin_amdgcn_exp2f(S2[0]), __builtin_amdgcn_exp2f(S2[1])),
                cvt_pk2(__builtin_amdgcn_exp2f(S2[2]), __builtin_amdgcn_exp2f(S2[3])),
                cvt_pk2(__builtin_amdgcn_exp2f(S2[4]), __builtin_amdgcn_exp2f(S2[5])),
                cvt_pk2(__builtin_amdgcn_exp2f(S2[6]), __builtin_amdgcn_exp2f(S2[7]))};
            pD.u = (uint4v){
                cvt_pk2(__builtin_amdgcn_exp2f(S2[8]),  __builtin_amdgcn_exp2f(S2[9])),
                cvt_pk2(__builtin_amdgcn_exp2f(S2[10]), __builtin_amdgcn_exp2f(S2[11])),
                cvt_pk2(__builtin_amdgcn_exp2f(S2[12]), __builtin_amdgcn_exp2f(S2[13])),
                cvt_pk2(__builtin_amdgcn_exp2f(S2[14]), __builtin_amdgcn_exp2f(S2[15]))};

            #pragma unroll
            for (int p = 0; p < 4; ++p) {
                short8 vf = *(short8*)(&Vt[m][it * 64 + p * 16 + hi * 8]);
                short8 pf = (p == 0) ? pA.s : (p == 1) ? pB.s : (p == 2) ? pC.s : pD.s;
                Oacc = __builtin_amdgcn_mfma_f32_32x32x16_bf16(vf, pf, Oacc, 0, 0, 0);
            }
        }
    }

    float Lq = __shfl(Oacc[8], m, 64);
    float inv = 1.0f / Lq;
    uint32_t o0 = cvt_pk2(Oacc[0] * inv, Oacc[1] * inv);
    uint32_t o1 = cvt_pk2(Oacc[2] * inv, Oacc[3] * inv);
    uint32_t o2 = cvt_pk2(Oacc[4] * inv, Oacc[5] * inv);
    uint32_t o3 = cvt_pk2(Oacc[6] * inv, Oacc[7] * inv);
    short* row = Out + ((size_t)(b * 2048 + qbase + m)) * 256 + h * 16;
    uint2 w0; w0.x = o0; w0.y = o1;
    uint2 w1; w1.x = o2; w1.y = o3;
    *(uint2*)(row + hi * 4) = w0;
    *(uint2*)(row + 8 + hi * 4) = w1;
}

// ---------------- launcher ----------------

extern "C" void kernel_launch(void* const* d_in, const int* in_sizes, int n_in,
                              void* d_out, int out_size, void* d_ws, size_t ws_size,
                              hipStream_t stream) {
    const float* x      = (const float*)d_in[0];
    const float* w_qkv  = (const float*)d_in[1];
    const float* b_qkv  = (const float*)d_in[2];
    const float* w_proj = (const float*)d_in[3];
    const float* b_proj = (const float*)d_in[4];
    float* out = (float*)d_out;

    short* wqkvT  = (short*)d_ws;          // 768*256
    short* wprojT = wqkvT + 196608;        // 256*256
    short* xb     = wprojT + 65536;        // (B*N, C) bf16
    short* Qb     = xb + 2097152;          // (B*H, N, D) bf16
    short* Kb     = Qb + 2097152;
    short* Vb     = Kb + 2097152;
    short* Ab     = Vb + 2097152;          // attention output (B,N,C) bf16

    cvtW_kernel<<<2048, 256, 0, stream>>>(w_qkv, w_proj, x, wqkvT, wprojT, xb);

    gemm2_kernel<128, 0><<<dim3(64, 6), 256, 0, stream>>>(xb, wqkvT, b_qkv,
                                                          Qb, Kb, Vb, nullptr);

    attn_kernel<<<dim3(16, 64), 256, 0, stream>>>(Qb, Kb, Vb, Ab);

    gemm2_kernel<64, 1><<<dim3(128, 2), 256, 0, stream>>>(Ab, wprojT, b_proj,
                                                          nullptr, nullptr, nullptr, out);
}

// Round 4
// 135.075 us; speedup vs baseline: 1.3052x; 1.0084x over previous
//
#include <hip/hip_runtime.h>
#include <stdint.h>

typedef __attribute__((ext_vector_type(8))) short short8;
typedef __attribute__((ext_vector_type(4))) short short4v;
typedef __attribute__((ext_vector_type(4))) float float4v;
typedef __attribute__((ext_vector_type(16))) float float16v;
typedef __attribute__((ext_vector_type(4))) uint32_t uint4v;

__device__ __forceinline__ short f2bf(float f) {
    union { float f; uint32_t u; } v; v.f = f;
    uint32_t u = v.u;
    uint32_t r = (u + 0x7fffu + ((u >> 16) & 1u)) >> 16;
    return (short)r;
}

#if __has_builtin(__builtin_amdgcn_cvt_pk_bf16_f32)
typedef __bf16 bf16x2_t __attribute__((ext_vector_type(2)));
__device__ __forceinline__ uint32_t cvt_pk2(float a, float b) {
    union { bf16x2_t v; uint32_t u; } c;
    c.v = __builtin_amdgcn_cvt_pk_bf16_f32(a, b);
    return c.u;
}
#else
__device__ __forceinline__ uint32_t cvt_pk2(float a, float b) {
    union { float f; uint32_t u; } x, y; x.f = a; y.f = b;
    return ((x.u + 0x8000u) >> 16) | ((y.u + 0x8000u) & 0xFFFF0000u);
}
#endif

// async 16B global -> LDS (DMA write: no LDS bank conflicts on the write side).
__device__ __forceinline__ void async_ld16(short* lds, const short* g) {
    __builtin_amdgcn_global_load_lds(
        (const __attribute__((address_space(1))) void*)g,
        (__attribute__((address_space(3))) void*)lds, 16, 0, 0);
}

// ---------------- coalesced weight transpose-convert (r16) ----------------
// r15's version read wqkv at stride 768*4B (one 64B line per 4B used, ~20 MB
// fetch for 3.4 MB of weights).  Now: 64x64 tile through LDS — reads coalesced
// (float4 along n), writes coalesced (short8 along k).  Stride-66 pad keeps the
// transposed read <=4-way and the write 2-way (free).
// Blocks 0..47: wqkv (256k x 768n).  Blocks 48..63: wproj (256 x 256).

__global__ __launch_bounds__(256) void cvtW_kernel(const float* __restrict__ wqkv,
                                                   const float* __restrict__ wproj,
                                                   short* __restrict__ outq,
                                                   short* __restrict__ outp) {
    __shared__ short T[64][66];
    int t = blockIdx.x;
    const float* src; short* dst; int srcld, k0, n0;
    if (t < 48) {
        k0 = (t & 3) * 64; n0 = (t >> 2) * 64;
        src = wqkv; srcld = 768; dst = outq;
    } else {
        int i = t - 48;
        k0 = (i & 3) * 64; n0 = (i >> 2) * 64;
        src = wproj; srcld = 256; dst = outp;
    }
    int row = threadIdx.x >> 2, seg = threadIdx.x & 3;
    const float* s = src + (size_t)(k0 + row) * srcld + n0 + seg * 16;
    float4 f0 = *(const float4*)s;
    float4 f1 = *(const float4*)(s + 4);
    float4 f2 = *(const float4*)(s + 8);
    float4 f3 = *(const float4*)(s + 12);
    uint32_t* tw = (uint32_t*)&T[row][seg * 16];
    tw[0] = cvt_pk2(f0.x, f0.y); tw[1] = cvt_pk2(f0.z, f0.w);
    tw[2] = cvt_pk2(f1.x, f1.y); tw[3] = cvt_pk2(f1.z, f1.w);
    tw[4] = cvt_pk2(f2.x, f2.y); tw[5] = cvt_pk2(f2.z, f2.w);
    tw[6] = cvt_pk2(f3.x, f3.y); tw[7] = cvt_pk2(f3.z, f3.w);
    __syncthreads();
    short tmp[16] __attribute__((aligned(16)));
    #pragma unroll
    for (int j = 0; j < 16; ++j) tmp[j] = T[seg * 16 + j][row];
    short* d = dst + (size_t)(n0 + row) * 256 + k0 + seg * 16;
    *(short8*)d       = *(short8*)&tmp[0];
    *(short8*)(d + 8) = *(short8*)&tmp[8];
}

// ---------------- GEMM v2 (r16): TM x 128 tile, BK=64, XOR swizzle ----------------
// MODE 0 (TM=128): A = x fp32, converted bf16 during reg-staged swizzled
//   ds_write_b128 (no separate conversion pass); outputs Q/K/V, Q * log2(e).
// MODE 1 (TM=64):  A = Ab bf16 via global_load_lds; output fp32 + bias.
// B always bf16 via global_load_lds with pre-swizzled global source col.

template<int TM, int MODE>
__global__ __launch_bounds__(256) void gemm2_kernel(
    const void* __restrict__ Ap, const short* __restrict__ Bt,
    const float* __restrict__ bias,
    short* __restrict__ outQ, short* __restrict__ outK, short* __restrict__ outV,
    float* __restrict__ outP)
{
    const int K = 256;
    const int MI = TM / 32;               // A-frags per wave
    int tid = threadIdx.x;
    int w = tid >> 6, lane = tid & 63;
    int wr = w >> 1, wc = w & 1;
    int quad = lane >> 4, lc = lane & 15;
    int m0 = blockIdx.x * TM, n0 = blockIdx.y * 128;

    __shared__ __align__(16) short As[TM * 64];
    __shared__ __align__(16) short Bs[128 * 64];

    float4v acc[MI][4];
    #pragma unroll
    for (int i = 0; i < MI; ++i)
        #pragma unroll
        for (int j = 0; j < 4; ++j) acc[i][j] = (float4v){0.f, 0.f, 0.f, 0.f};

    int l8 = lane >> 3, l7 = lane & 7;
    int scol = ((l7 ^ l8) * 8);           // pre-swizzled global col (elements)

    for (int kt = 0; kt < 4; ++kt) {
        int c = kt * 64;
        __syncthreads();                   // prior-iter frag reads complete
        if (MODE == 0) {
            const float* Af = (const float*)Ap;
            #pragma unroll
            for (int i = 0; i < 4; ++i) {
                int row = i * 32 + (tid >> 3);
                int seg = tid & 7;
                const float* src = Af + (size_t)(m0 + row) * K + c + seg * 8;
                float4 f0 = *(const float4*)src;
                float4 f1 = *(const float4*)(src + 4);
                uint4v u; u.x = cvt_pk2(f0.x, f0.y); u.y = cvt_pk2(f0.z, f0.w);
                u.z = cvt_pk2(f1.x, f1.y); u.w = cvt_pk2(f1.z, f1.w);
                *(uint4v*)(&As[row * 64 + ((seg ^ (row & 7)) * 8)]) = u;
            }
        } else {
            #pragma unroll
            for (int i = 0; i < TM / 32; ++i) {
                int row = i * 32 + w * 8 + l8;     // row&7 == l8
                async_ld16(&As[row * 64 + l7 * 8],
                           (const short*)Ap + (size_t)(m0 + row) * K + c + scol);
            }
        }
        #pragma unroll
        for (int i = 0; i < 4; ++i) {
            int row = i * 32 + w * 8 + l8;
            async_ld16(&Bs[row * 64 + l7 * 8],
                       Bt + (size_t)(n0 + row) * K + c + scol);
        }
        __syncthreads();                   // drain -> tile visible

        #pragma unroll
        for (int ks = 0; ks < 2; ++ks) {
            short8 af[MI], bf[4];
            #pragma unroll
            for (int i = 0; i < MI; ++i) {
                int r = wr * (TM / 2) + i * 16 + lc;
                af[i] = *(short8*)(&As[r * 64 + (((ks * 4 + quad) ^ (r & 7)) * 8)]);
            }
            #pragma unroll
            for (int j = 0; j < 4; ++j) {
                int r = wc * 64 + j * 16 + lc;
                bf[j] = *(short8*)(&Bs[r * 64 + (((ks * 4 + quad) ^ (r & 7)) * 8)]);
            }
            #pragma unroll
            for (int i = 0; i < MI; ++i)
                #pragma unroll
                for (int j = 0; j < 4; ++j)
                    acc[i][j] = __builtin_amdgcn_mfma_f32_16x16x32_bf16(af[i], bf[j], acc[i][j], 0, 0, 0);
        }
    }

    #pragma unroll
    for (int i = 0; i < MI; ++i) {
        #pragma unroll
        for (int j = 0; j < 4; ++j) {
            int cg = n0 + wc * 64 + j * 16 + lc;
            float bv = bias[cg];
            #pragma unroll
            for (int r = 0; r < 4; ++r) {
                int rg = m0 + wr * (TM / 2) + i * 16 + quad * 4 + r;
                float val = acc[i][j][r] + bv;
                if (MODE == 0) {
                    int sq = cg >> 8, rem = cg & 255, h = rem >> 4, d = rem & 15;
                    int b = rg >> 11, n = rg & 2047;
                    if (sq == 0) val *= 1.4426950408889634f;  // fold log2(e) into Q
                    short* dst = (sq == 0) ? outQ : ((sq == 1) ? outK : outV);
                    dst[((((size_t)b * 16 + h) * 2048 + n) << 4) + d] = f2bf(val);
                } else {
                    outP[(size_t)rg * 256 + cg] = val;
                }
            }
        }
    }
}

// ---------------- flash attention (r15 structure — best measured: 57.6us) --------
// Register-capped at ~128 unified VGPR+AGPR/wave -> 4 waves/SIMD; split-K (R2)
// and in-block split (R1) both net-negative.  Main loop frozen.

__global__ __launch_bounds__(256) void attn_kernel(
    const short* __restrict__ Q, const short* __restrict__ Kp, const short* __restrict__ V,
    short* __restrict__ Out)
{
    const int N = 2048;
    int bh = blockIdx.y;
    int b = bh >> 4, h = bh & 15;
    int tid = threadIdx.x;
    int wave = tid >> 6, lane = tid & 63;
    int m = lane & 31, hi = lane >> 5;
    int qbase = blockIdx.x * 128 + wave * 32;

    const short* Qh = Q + (size_t)bh * N * 16;
    const short* Kh = Kp + (size_t)bh * N * 16;
    const short* Vh = V + (size_t)bh * N * 16;

    __shared__ __align__(16) short Vt[32][264];

    for (int idx = tid; idx < 16 * 264; idx += 256) {
        int row = 16 + idx / 264;
        int col = idx - (row - 16) * 264;
        Vt[row][col] = (row == 16) ? (short)0x3F80 : (short)0;
    }

    short8 qf = *(const short8*)(Qh + (size_t)(qbase + m) * 16 + hi * 8);

    float16v Oacc, zf;
    #pragma unroll
    for (int j = 0; j < 16; ++j) { Oacc[j] = 0.f; zf[j] = 0.f; }

    int sd = tid & 15, sa = tid >> 4;
    int kb = ((sa & 1) << 3) | (((sa >> 1) & 1) << 2) | ((sa >> 2) << 4);

    short4v vpack[4];
    #pragma unroll
    for (int cc = 0; cc < 4; ++cc) {
        const short* vp = Vh + (size_t)(cc * 64 + kb) * 16 + sd;
        vpack[cc].x = vp[0]; vpack[cc].y = vp[16];
        vpack[cc].z = vp[32]; vpack[cc].w = vp[48];
    }

    short8 kf1 = *(const short8*)(Kh + (size_t)m * 16 + hi * 8);
    short8 kf2 = *(const short8*)(Kh + (size_t)(32 + m) * 16 + hi * 8);

    for (int sc = 0; sc < N; sc += 256) {
        __syncthreads();
        #pragma unroll
        for (int cc = 0; cc < 4; ++cc)
            *(short4v*)(&Vt[sd][cc * 64 + sa * 4]) = vpack[cc];
        if (sc + 256 < N) {
            #pragma unroll
            for (int cc = 0; cc < 4; ++cc) {
                const short* vp = Vh + (size_t)(sc + 256 + cc * 64 + kb) * 16 + sd;
                vpack[cc].x = vp[0]; vpack[cc].y = vp[16];
                vpack[cc].z = vp[32]; vpack[cc].w = vp[48];
            }
        }
        __syncthreads();

        #pragma unroll
        for (int it = 0; it < 4; ++it) {
            int c = sc + it * 64;
            int cn = (c + 64) & (N - 1);

            float16v S1 = __builtin_amdgcn_mfma_f32_32x32x16_bf16(kf1, qf, zf, 0, 0, 0);
            float16v S2 = __builtin_amdgcn_mfma_f32_32x32x16_bf16(kf2, qf, zf, 0, 0, 0);

            kf1 = *(const short8*)(Kh + (size_t)(cn + m) * 16 + hi * 8);
            kf2 = *(const short8*)(Kh + (size_t)(cn + 32 + m) * 16 + hi * 8);

            union { uint4v u; short8 s; } pA, pB, pC, pD;
            pA.u = (uint4v){
                cvt_pk2(__builtin_amdgcn_exp2f(S1[0]), __builtin_amdgcn_exp2f(S1[1])),
                cvt_pk2(__builtin_amdgcn_exp2f(S1[2]), __builtin_amdgcn_exp2f(S1[3])),
                cvt_pk2(__builtin_amdgcn_exp2f(S1[4]), __builtin_amdgcn_exp2f(S1[5])),
                cvt_pk2(__builtin_amdgcn_exp2f(S1[6]), __builtin_amdgcn_exp2f(S1[7]))};
            pB.u = (uint4v){
                cvt_pk2(__builtin_amdgcn_exp2f(S1[8]),  __builtin_amdgcn_exp2f(S1[9])),
                cvt_pk2(__builtin_amdgcn_exp2f(S1[10]), __builtin_amdgcn_exp2f(S1[11])),
                cvt_pk2(__builtin_amdgcn_exp2f(S1[12]), __builtin_amdgcn_exp2f(S1[13])),
                cvt_pk2(__builtin_amdgcn_exp2f(S1[14]), __builtin_amdgcn_exp2f(S1[15]))};
            pC.u = (uint4v){
                cvt_pk2(__builtin_amdgcn_exp2f(S2[0]), __builtin_amdgcn_exp2f(S2[1])),
                cvt_pk2(__builtin_amdgcn_exp2f(S2[2]), __builtin_amdgcn_exp2f(S2[3])),
                cvt_pk2(__builtin_amdgcn_exp2f(S2[4]), __builtin_amdgcn_exp2f(S2[5])),
                cvt_pk2(__builtin_amdgcn_exp2f(S2[6]), __builtin_amdgcn_exp2f(S2[7]))};
            pD.u = (uint4v){
                cvt_pk2(__builtin_amdgcn_exp2f(S2[8]),  __builtin_amdgcn_exp2f(S2[9])),
                cvt_pk2(__builtin_amdgcn_exp2f(S2[10]), __builtin_amdgcn_exp2f(S2[11])),
                cvt_pk2(__builtin_amdgcn_exp2f(S2[12]), __builtin_amdgcn_exp2f(S2[13])),
                cvt_pk2(__builtin_amdgcn_exp2f(S2[14]), __builtin_amdgcn_exp2f(S2[15]))};

            #pragma unroll
            for (int p = 0; p < 4; ++p) {
                short8 vf = *(short8*)(&Vt[m][it * 64 + p * 16 + hi * 8]);
                short8 pf = (p == 0) ? pA.s : (p == 1) ? pB.s : (p == 2) ? pC.s : pD.s;
                Oacc = __builtin_amdgcn_mfma_f32_32x32x16_bf16(vf, pf, Oacc, 0, 0, 0);
            }
        }
    }

    float Lq = __shfl(Oacc[8], m, 64);
    float inv = 1.0f / Lq;
    uint32_t o0 = cvt_pk2(Oacc[0] * inv, Oacc[1] * inv);
    uint32_t o1 = cvt_pk2(Oacc[2] * inv, Oacc[3] * inv);
    uint32_t o2 = cvt_pk2(Oacc[4] * inv, Oacc[5] * inv);
    uint32_t o3 = cvt_pk2(Oacc[6] * inv, Oacc[7] * inv);
    short* row = Out + ((size_t)(b * 2048 + qbase + m)) * 256 + h * 16;
    uint2 w0; w0.x = o0; w0.y = o1;
    uint2 w1; w1.x = o2; w1.y = o3;
    *(uint2*)(row + hi * 4) = w0;
    *(uint2*)(row + 8 + hi * 4) = w1;
}

// ---------------- launcher ----------------

extern "C" void kernel_launch(void* const* d_in, const int* in_sizes, int n_in,
                              void* d_out, int out_size, void* d_ws, size_t ws_size,
                              hipStream_t stream) {
    const float* x      = (const float*)d_in[0];
    const float* w_qkv  = (const float*)d_in[1];
    const float* b_qkv  = (const float*)d_in[2];
    const float* w_proj = (const float*)d_in[3];
    const float* b_proj = (const float*)d_in[4];
    float* out = (float*)d_out;

    short* wqkvT  = (short*)d_ws;          // 768*256
    short* wprojT = wqkvT + 196608;        // 256*256
    short* Qb     = wprojT + 65536;        // (B*H, N, D) bf16
    short* Kb     = Qb + 2097152;
    short* Vb     = Kb + 2097152;
    short* Ab     = Vb + 2097152;          // attention output (B,N,C) bf16

    cvtW_kernel<<<64, 256, 0, stream>>>(w_qkv, w_proj, wqkvT, wprojT);

    gemm2_kernel<128, 0><<<dim3(64, 6), 256, 0, stream>>>(x, wqkvT, b_qkv,
                                                          Qb, Kb, Vb, nullptr);

    attn_kernel<<<dim3(16, 64), 256, 0, stream>>>(Qb, Kb, Vb, Ab);

    gemm2_kernel<64, 1><<<dim3(128, 2), 256, 0, stream>>>(Ab, wprojT, b_proj,
                                                          nullptr, nullptr, nullptr, out);
}

// Round 5
// 134.012 us; speedup vs baseline: 1.3156x; 1.0079x over previous
//
#include <hip/hip_runtime.h>
#include <stdint.h>

typedef __attribute__((ext_vector_type(8))) short short8;
typedef __attribute__((ext_vector_type(4))) short short4v;
typedef __attribute__((ext_vector_type(4))) float float4v;
typedef __attribute__((ext_vector_type(16))) float float16v;
typedef __attribute__((ext_vector_type(4))) uint32_t uint4v;

__device__ __forceinline__ short f2bf(float f) {
    union { float f; uint32_t u; } v; v.f = f;
    uint32_t u = v.u;
    uint32_t r = (u + 0x7fffu + ((u >> 16) & 1u)) >> 16;
    return (short)r;
}

#if __has_builtin(__builtin_amdgcn_cvt_pk_bf16_f32)
typedef __bf16 bf16x2_t __attribute__((ext_vector_type(2)));
__device__ __forceinline__ uint32_t cvt_pk2(float a, float b) {
    union { bf16x2_t v; uint32_t u; } c;
    c.v = __builtin_amdgcn_cvt_pk_bf16_f32(a, b);
    return c.u;
}
#else
__device__ __forceinline__ uint32_t cvt_pk2(float a, float b) {
    union { float f; uint32_t u; } x, y; x.f = a; y.f = b;
    return ((x.u + 0x8000u) >> 16) | ((y.u + 0x8000u) & 0xFFFF0000u);
}
#endif

// ---------------- coalesced weight transpose-convert (r16) ----------------
// 64x64 tile through LDS — reads coalesced (float4 along n), writes coalesced
// (short8 along k).  Stride-66 pad keeps the transposed read <=4-way.
// Blocks 0..47: wqkv (256k x 768n).  Blocks 48..63: wproj (256 x 256).

__global__ __launch_bounds__(256) void cvtW_kernel(const float* __restrict__ wqkv,
                                                   const float* __restrict__ wproj,
                                                   short* __restrict__ outq,
                                                   short* __restrict__ outp) {
    __shared__ short T[64][66];
    int t = blockIdx.x;
    const float* src; short* dst; int srcld, k0, n0;
    if (t < 48) {
        k0 = (t & 3) * 64; n0 = (t >> 2) * 64;
        src = wqkv; srcld = 768; dst = outq;
    } else {
        int i = t - 48;
        k0 = (i & 3) * 64; n0 = (i >> 2) * 64;
        src = wproj; srcld = 256; dst = outp;
    }
    int row = threadIdx.x >> 2, seg = threadIdx.x & 3;
    const float* s = src + (size_t)(k0 + row) * srcld + n0 + seg * 16;
    float4 f0 = *(const float4*)s;
    float4 f1 = *(const float4*)(s + 4);
    float4 f2 = *(const float4*)(s + 8);
    float4 f3 = *(const float4*)(s + 12);
    uint32_t* tw = (uint32_t*)&T[row][seg * 16];
    tw[0] = cvt_pk2(f0.x, f0.y); tw[1] = cvt_pk2(f0.z, f0.w);
    tw[2] = cvt_pk2(f1.x, f1.y); tw[3] = cvt_pk2(f1.z, f1.w);
    tw[4] = cvt_pk2(f2.x, f2.y); tw[5] = cvt_pk2(f2.z, f2.w);
    tw[6] = cvt_pk2(f3.x, f3.y); tw[7] = cvt_pk2(f3.z, f3.w);
    __syncthreads();
    short tmp[16] __attribute__((aligned(16)));
    #pragma unroll
    for (int j = 0; j < 16; ++j) tmp[j] = T[seg * 16 + j][row];
    short* d = dst + (size_t)(n0 + row) * 256 + k0 + seg * 16;
    *(short8*)d       = *(short8*)&tmp[0];
    *(short8*)(d + 8) = *(short8*)&tmp[8];
}

// ---------------- GEMM (r5 structure — best measured): 64x64 tile ----------------
// REVERTED from gemm2 (R3/R4): the 128-wide-tile + global_load_lds structure at
// K=256 ran ~5us slower net — 384 blocks = 1.5/CU loses the TLP that hides
// staging latency; 4 K-iterations never amortize the deep tile.  r5's 1536
// blocks at 6/CU is the measured winner at this shape.
// MODE 0: A fp32 (x), bf16-converted during LDS staging; outputs Q/K/V
//         (B,H,N,D), Q pre-scaled by log2(e).  MODE 1: A bf16; fp32 out.

template<int MODE>
__global__ __launch_bounds__(256) void gemm_kernel(
    const void* __restrict__ Ap, const short* __restrict__ Bt,
    const float* __restrict__ bias,
    short* __restrict__ outQ, short* __restrict__ outK, short* __restrict__ outV,
    float* __restrict__ outP)
{
    const int K = 256;
    int m0 = blockIdx.x * 64;
    int n0 = blockIdx.y * 64;
    int tid = threadIdx.x;
    int wave = tid >> 6, lane = tid & 63, quad = lane >> 4, lc = lane & 15;

    __shared__ __align__(16) short As[64 * 48];
    __shared__ __align__(16) short Bs[64 * 48];

    float4v acc[4];
    #pragma unroll
    for (int t = 0; t < 4; ++t) acc[t] = (float4v){0.f, 0.f, 0.f, 0.f};

    int srow = tid >> 2, sseg = tid & 3;

    for (int c = 0; c < K; c += 32) {
        __syncthreads();
        if (MODE == 0) {
            const float* src = (const float*)Ap + (size_t)(m0 + srow) * K + c + sseg * 8;
            float4 f0 = *(const float4*)src;
            float4 f1 = *(const float4*)(src + 4);
            uint4v u; u.x = cvt_pk2(f0.x, f0.y); u.y = cvt_pk2(f0.z, f0.w);
            u.z = cvt_pk2(f1.x, f1.y); u.w = cvt_pk2(f1.z, f1.w);
            *(uint4v*)(&As[srow * 48 + sseg * 8]) = u;
        } else {
            *(short8*)(&As[srow * 48 + sseg * 8]) =
                *(const short8*)((const short*)Ap + (size_t)(m0 + srow) * K + c + sseg * 8);
        }
        *(short8*)(&Bs[srow * 48 + sseg * 8]) =
            *(const short8*)(Bt + (size_t)(n0 + srow) * K + c + sseg * 8);
        __syncthreads();

        short8 af = *(short8*)(&As[(wave * 16 + lc) * 48 + quad * 8]);
        #pragma unroll
        for (int t = 0; t < 4; ++t) {
            short8 bf = *(short8*)(&Bs[(t * 16 + lc) * 48 + quad * 8]);
            acc[t] = __builtin_amdgcn_mfma_f32_16x16x32_bf16(af, bf, acc[t], 0, 0, 0);
        }
    }

    #pragma unroll
    for (int t = 0; t < 4; ++t) {
        int cg = n0 + t * 16 + lc;
        float bv = bias[cg];
        #pragma unroll
        for (int r = 0; r < 4; ++r) {
            int rg = m0 + wave * 16 + quad * 4 + r;
            float val = acc[t][r] + bv;
            if (MODE == 0) {
                int sq = cg >> 8, rem = cg & 255, h = rem >> 4, d = rem & 15;
                int b = rg >> 11, n = rg & 2047;
                if (sq == 0) val *= 1.4426950408889634f;  // fold log2(e) into Q
                short* dst = (sq == 0) ? outQ : ((sq == 1) ? outK : outV);
                dst[((((size_t)b * 16 + h) * 2048 + n) << 4) + d] = f2bf(val);
            } else {
                outP[(size_t)rg * 256 + cg] = val;
            }
        }
    }
}

// ---------------- flash attention (r15 structure — best measured: 57.5us) --------
// Register-capped at ~128 unified VGPR+AGPR/wave -> 4 waves/SIMD; split-K (R2)
// and in-block split (R1) both net-negative.  VALU model: 268M lane-exps at
// trans quarter-rate ~= 28us floor; 57.5 measured.  Main loop frozen.
// Padded Vt (32 rows: row 16 = 1.0, 17..31 = 0, written once) = isolated -3us.

__global__ __launch_bounds__(256) void attn_kernel(
    const short* __restrict__ Q, const short* __restrict__ Kp, const short* __restrict__ V,
    short* __restrict__ Out)
{
    const int N = 2048;
    int bh = blockIdx.y;
    int b = bh >> 4, h = bh & 15;
    int tid = threadIdx.x;
    int wave = tid >> 6, lane = tid & 63;
    int m = lane & 31, hi = lane >> 5;
    int qbase = blockIdx.x * 128 + wave * 32;

    const short* Qh = Q + (size_t)bh * N * 16;
    const short* Kh = Kp + (size_t)bh * N * 16;
    const short* Vh = V + (size_t)bh * N * 16;

    __shared__ __align__(16) short Vt[32][264];

    for (int idx = tid; idx < 16 * 264; idx += 256) {
        int row = 16 + idx / 264;
        int col = idx - (row - 16) * 264;
        Vt[row][col] = (row == 16) ? (short)0x3F80 : (short)0;
    }

    short8 qf = *(const short8*)(Qh + (size_t)(qbase + m) * 16 + hi * 8);

    float16v Oacc, zf;
    #pragma unroll
    for (int j = 0; j < 16; ++j) { Oacc[j] = 0.f; zf[j] = 0.f; }

    int sd = tid & 15, sa = tid >> 4;
    int kb = ((sa & 1) << 3) | (((sa >> 1) & 1) << 2) | ((sa >> 2) << 4);

    short4v vpack[4];
    #pragma unroll
    for (int cc = 0; cc < 4; ++cc) {
        const short* vp = Vh + (size_t)(cc * 64 + kb) * 16 + sd;
        vpack[cc].x = vp[0]; vpack[cc].y = vp[16];
        vpack[cc].z = vp[32]; vpack[cc].w = vp[48];
    }

    short8 kf1 = *(const short8*)(Kh + (size_t)m * 16 + hi * 8);
    short8 kf2 = *(const short8*)(Kh + (size_t)(32 + m) * 16 + hi * 8);

    for (int sc = 0; sc < N; sc += 256) {
        __syncthreads();
        #pragma unroll
        for (int cc = 0; cc < 4; ++cc)
            *(short4v*)(&Vt[sd][cc * 64 + sa * 4]) = vpack[cc];
        if (sc + 256 < N) {
            #pragma unroll
            for (int cc = 0; cc < 4; ++cc) {
                const short* vp = Vh + (size_t)(sc + 256 + cc * 64 + kb) * 16 + sd;
                vpack[cc].x = vp[0]; vpack[cc].y = vp[16];
                vpack[cc].z = vp[32]; vpack[cc].w = vp[48];
            }
        }
        __syncthreads();

        #pragma unroll
        for (int it = 0; it < 4; ++it) {
            int c = sc + it * 64;
            int cn = (c + 64) & (N - 1);

            float16v S1 = __builtin_amdgcn_mfma_f32_32x32x16_bf16(kf1, qf, zf, 0, 0, 0);
            float16v S2 = __builtin_amdgcn_mfma_f32_32x32x16_bf16(kf2, qf, zf, 0, 0, 0);

            kf1 = *(const short8*)(Kh + (size_t)(cn + m) * 16 + hi * 8);
            kf2 = *(const short8*)(Kh + (size_t)(cn + 32 + m) * 16 + hi * 8);

            union { uint4v u; short8 s; } pA, pB, pC, pD;
            pA.u = (uint4v){
                cvt_pk2(__builtin_amdgcn_exp2f(S1[0]), __builtin_amdgcn_exp2f(S1[1])),
                cvt_pk2(__builtin_amdgcn_exp2f(S1[2]), __builtin_amdgcn_exp2f(S1[3])),
                cvt_pk2(__builtin_amdgcn_exp2f(S1[4]), __builtin_amdgcn_exp2f(S1[5])),
                cvt_pk2(__builtin_amdgcn_exp2f(S1[6]), __builtin_amdgcn_exp2f(S1[7]))};
            pB.u = (uint4v){
                cvt_pk2(__builtin_amdgcn_exp2f(S1[8]),  __builtin_amdgcn_exp2f(S1[9])),
                cvt_pk2(__builtin_amdgcn_exp2f(S1[10]), __builtin_amdgcn_exp2f(S1[11])),
                cvt_pk2(__builtin_amdgcn_exp2f(S1[12]), __builtin_amdgcn_exp2f(S1[13])),
                cvt_pk2(__builtin_amdgcn_exp2f(S1[14]), __builtin_amdgcn_exp2f(S1[15]))};
            pC.u = (uint4v){
                cvt_pk2(__builtin_amdgcn_exp2f(S2[0]), __builtin_amdgcn_exp2f(S2[1])),
                cvt_pk2(__builtin_amdgcn_exp2f(S2[2]), __builtin_amdgcn_exp2f(S2[3])),
                cvt_pk2(__builtin_amdgcn_exp2f(S2[4]), __builtin_amdgcn_exp2f(S2[5])),
                cvt_pk2(__builtin_amdgcn_exp2f(S2[6]), __builtin_amdgcn_exp2f(S2[7]))};
            pD.u = (uint4v){
                cvt_pk2(__builtin_amdgcn_exp2f(S2[8]),  __builtin_amdgcn_exp2f(S2[9])),
                cvt_pk2(__builtin_amdgcn_exp2f(S2[10]), __builtin_amdgcn_exp2f(S2[11])),
                cvt_pk2(__builtin_amdgcn_exp2f(S2[12]), __builtin_amdgcn_exp2f(S2[13])),
                cvt_pk2(__builtin_amdgcn_exp2f(S2[14]), __builtin_amdgcn_exp2f(S2[15]))};

            #pragma unroll
            for (int p = 0; p < 4; ++p) {
                short8 vf = *(short8*)(&Vt[m][it * 64 + p * 16 + hi * 8]);
                short8 pf = (p == 0) ? pA.s : (p == 1) ? pB.s : (p == 2) ? pC.s : pD.s;
                Oacc = __builtin_amdgcn_mfma_f32_32x32x16_bf16(vf, pf, Oacc, 0, 0, 0);
            }
        }
    }

    float Lq = __shfl(Oacc[8], m, 64);
    float inv = 1.0f / Lq;
    uint32_t o0 = cvt_pk2(Oacc[0] * inv, Oacc[1] * inv);
    uint32_t o1 = cvt_pk2(Oacc[2] * inv, Oacc[3] * inv);
    uint32_t o2 = cvt_pk2(Oacc[4] * inv, Oacc[5] * inv);
    uint32_t o3 = cvt_pk2(Oacc[6] * inv, Oacc[7] * inv);
    short* row = Out + ((size_t)(b * 2048 + qbase + m)) * 256 + h * 16;
    uint2 w0; w0.x = o0; w0.y = o1;
    uint2 w1; w1.x = o2; w1.y = o3;
    *(uint2*)(row + hi * 4) = w0;
    *(uint2*)(row + 8 + hi * 4) = w1;
}

// ---------------- launcher ----------------

extern "C" void kernel_launch(void* const* d_in, const int* in_sizes, int n_in,
                              void* d_out, int out_size, void* d_ws, size_t ws_size,
                              hipStream_t stream) {
    const float* x      = (const float*)d_in[0];
    const float* w_qkv  = (const float*)d_in[1];
    const float* b_qkv  = (const float*)d_in[2];
    const float* w_proj = (const float*)d_in[3];
    const float* b_proj = (const float*)d_in[4];
    float* out = (float*)d_out;

    short* wqkvT  = (short*)d_ws;          // 768*256
    short* wprojT = wqkvT + 196608;        // 256*256
    short* Qb     = wprojT + 65536;        // (B*H, N, D) bf16
    short* Kb     = Qb + 2097152;
    short* Vb     = Kb + 2097152;
    short* Ab     = Vb + 2097152;          // attention output (B,N,C) bf16

    cvtW_kernel<<<64, 256, 0, stream>>>(w_qkv, w_proj, wqkvT, wprojT);

    gemm_kernel<0><<<dim3(128, 12), 256, 0, stream>>>(x, wqkvT, b_qkv, Qb, Kb, Vb, nullptr);

    attn_kernel<<<dim3(16, 64), 256, 0, stream>>>(Qb, Kb, Vb, Ab);

    gemm_kernel<1><<<dim3(128, 4), 256, 0, stream>>>(Ab, wprojT, b_proj,
                                                     nullptr, nullptr, nullptr, out);
}

// Round 6
// 128.603 us; speedup vs baseline: 1.3709x; 1.0421x over previous
//
#include <hip/hip_runtime.h>
#include <stdint.h>

typedef __attribute__((ext_vector_type(8))) short short8;
typedef __attribute__((ext_vector_type(4))) short short4v;
typedef __attribute__((ext_vector_type(4))) float float4v;
typedef __attribute__((ext_vector_type(16))) float float16v;
typedef __attribute__((ext_vector_type(4))) uint32_t uint4v;

__device__ __forceinline__ short f2bf(float f) {
    union { float f; uint32_t u; } v; v.f = f;
    uint32_t u = v.u;
    uint32_t r = (u + 0x7fffu + ((u >> 16) & 1u)) >> 16;
    return (short)r;
}

#if __has_builtin(__builtin_amdgcn_cvt_pk_bf16_f32)
typedef __bf16 bf16x2_t __attribute__((ext_vector_type(2)));
__device__ __forceinline__ uint32_t cvt_pk2(float a, float b) {
    union { bf16x2_t v; uint32_t u; } c;
    c.v = __builtin_amdgcn_cvt_pk_bf16_f32(a, b);
    return c.u;
}
#else
__device__ __forceinline__ uint32_t cvt_pk2(float a, float b) {
    union { float f; uint32_t u; } x, y; x.f = a; y.f = b;
    return ((x.u + 0x8000u) >> 16) | ((y.u + 0x8000u) & 0xFFFF0000u);
}
#endif

// ---------------- coalesced weight transpose-convert (r16) ----------------

__global__ __launch_bounds__(256) void cvtW_kernel(const float* __restrict__ wqkv,
                                                   const float* __restrict__ wproj,
                                                   short* __restrict__ outq,
                                                   short* __restrict__ outp) {
    __shared__ short T[64][66];
    int t = blockIdx.x;
    const float* src; short* dst; int srcld, k0, n0;
    if (t < 48) {
        k0 = (t & 3) * 64; n0 = (t >> 2) * 64;
        src = wqkv; srcld = 768; dst = outq;
    } else {
        int i = t - 48;
        k0 = (i & 3) * 64; n0 = (i >> 2) * 64;
        src = wproj; srcld = 256; dst = outp;
    }
    int row = threadIdx.x >> 2, seg = threadIdx.x & 3;
    const float* s = src + (size_t)(k0 + row) * srcld + n0 + seg * 16;
    float4 f0 = *(const float4*)s;
    float4 f1 = *(const float4*)(s + 4);
    float4 f2 = *(const float4*)(s + 8);
    float4 f3 = *(const float4*)(s + 12);
    uint32_t* tw = (uint32_t*)&T[row][seg * 16];
    tw[0] = cvt_pk2(f0.x, f0.y); tw[1] = cvt_pk2(f0.z, f0.w);
    tw[2] = cvt_pk2(f1.x, f1.y); tw[3] = cvt_pk2(f1.z, f1.w);
    tw[4] = cvt_pk2(f2.x, f2.y); tw[5] = cvt_pk2(f2.z, f2.w);
    tw[6] = cvt_pk2(f3.x, f3.y); tw[7] = cvt_pk2(f3.z, f3.w);
    __syncthreads();
    short tmp[16] __attribute__((aligned(16)));
    #pragma unroll
    for (int j = 0; j < 16; ++j) tmp[j] = T[seg * 16 + j][row];
    short* d = dst + (size_t)(n0 + row) * 256 + k0 + seg * 16;
    *(short8*)d       = *(short8*)&tmp[0];
    *(short8*)(d + 8) = *(short8*)&tmp[8];
}

// ---------------- GEMM (r5 structure — best measured): 64x64 tile ----------------
// Three GEMM variants measured (r5 / gemm2+xb / gemm2): non-attn block is
// insensitive within ±3us at this K=256 shape.  Frozen on r5.

template<int MODE>
__global__ __launch_bounds__(256) void gemm_kernel(
    const void* __restrict__ Ap, const short* __restrict__ Bt,
    const float* __restrict__ bias,
    short* __restrict__ outQ, short* __restrict__ outK, short* __restrict__ outV,
    float* __restrict__ outP)
{
    const int K = 256;
    int m0 = blockIdx.x * 64;
    int n0 = blockIdx.y * 64;
    int tid = threadIdx.x;
    int wave = tid >> 6, lane = tid & 63, quad = lane >> 4, lc = lane & 15;

    __shared__ __align__(16) short As[64 * 48];
    __shared__ __align__(16) short Bs[64 * 48];

    float4v acc[4];
    #pragma unroll
    for (int t = 0; t < 4; ++t) acc[t] = (float4v){0.f, 0.f, 0.f, 0.f};

    int srow = tid >> 2, sseg = tid & 3;

    for (int c = 0; c < K; c += 32) {
        __syncthreads();
        if (MODE == 0) {
            const float* src = (const float*)Ap + (size_t)(m0 + srow) * K + c + sseg * 8;
            float4 f0 = *(const float4*)src;
            float4 f1 = *(const float4*)(src + 4);
            uint4v u; u.x = cvt_pk2(f0.x, f0.y); u.y = cvt_pk2(f0.z, f0.w);
            u.z = cvt_pk2(f1.x, f1.y); u.w = cvt_pk2(f1.z, f1.w);
            *(uint4v*)(&As[srow * 48 + sseg * 8]) = u;
        } else {
            *(short8*)(&As[srow * 48 + sseg * 8]) =
                *(const short8*)((const short*)Ap + (size_t)(m0 + srow) * K + c + sseg * 8);
        }
        *(short8*)(&Bs[srow * 48 + sseg * 8]) =
            *(const short8*)(Bt + (size_t)(n0 + srow) * K + c + sseg * 8);
        __syncthreads();

        short8 af = *(short8*)(&As[(wave * 16 + lc) * 48 + quad * 8]);
        #pragma unroll
        for (int t = 0; t < 4; ++t) {
            short8 bf = *(short8*)(&Bs[(t * 16 + lc) * 48 + quad * 8]);
            acc[t] = __builtin_amdgcn_mfma_f32_16x16x32_bf16(af, bf, acc[t], 0, 0, 0);
        }
    }

    #pragma unroll
    for (int t = 0; t < 4; ++t) {
        int cg = n0 + t * 16 + lc;
        float bv = bias[cg];
        #pragma unroll
        for (int r = 0; r < 4; ++r) {
            int rg = m0 + wave * 16 + quad * 4 + r;
            float val = acc[t][r] + bv;
            if (MODE == 0) {
                int sq = cg >> 8, rem = cg & 255, h = rem >> 4, d = rem & 15;
                int b = rg >> 11, n = rg & 2047;
                if (sq == 0) val *= 1.4426950408889634f;  // fold log2(e) into Q
                short* dst = (sq == 0) ? outQ : ((sq == 1) ? outK : outV);
                dst[((((size_t)b * 16 + h) * 2048 + n) << 4) + d] = f2bf(val);
            } else {
                outP[(size_t)rg * 256 + cg] = val;
            }
        }
    }
}

// ---------------- flash attention (r17: register-thinned, 3 waves/EU) ------------
// R5 counter re-read: Occupancy 28% = 2 waves/SIMD -> unified VGPR+AGPR footprint
// just over 128/wave (pool 512/SIMD).  At 2 waves the trans pipe is idle half the
// time (exp issue ~14us vs 58us measured) — dependency-stall bound.  Fix: shave
// ~20-30 regs to cross the 170 (3-wave) boundary:
//   * exp+pack+PV interleaved PER p-block: pack liveness 16 -> 4 dwords
//   * __launch_bounds__(256, 3): 170-reg cap; allocator remats zf, reorders
// R1's lesson respected: (512,8) demanded 64 regs (2.5x over -> spill).  This
// asks ~15% — spill tripwire is WRITE_SIZE (must stay 4 MB).

__global__ __launch_bounds__(256, 3) void attn_kernel(
    const short* __restrict__ Q, const short* __restrict__ Kp, const short* __restrict__ V,
    short* __restrict__ Out)
{
    const int N = 2048;
    int bh = blockIdx.y;
    int b = bh >> 4, h = bh & 15;
    int tid = threadIdx.x;
    int wave = tid >> 6, lane = tid & 63;
    int m = lane & 31, hi = lane >> 5;
    int qbase = blockIdx.x * 128 + wave * 32;

    const short* Qh = Q + (size_t)bh * N * 16;
    const short* Kh = Kp + (size_t)bh * N * 16;
    const short* Vh = V + (size_t)bh * N * 16;

    __shared__ __align__(16) short Vt[32][264];

    for (int idx = tid; idx < 16 * 264; idx += 256) {
        int row = 16 + idx / 264;
        int col = idx - (row - 16) * 264;
        Vt[row][col] = (row == 16) ? (short)0x3F80 : (short)0;
    }

    short8 qf = *(const short8*)(Qh + (size_t)(qbase + m) * 16 + hi * 8);

    float16v Oacc, zf;
    #pragma unroll
    for (int j = 0; j < 16; ++j) { Oacc[j] = 0.f; zf[j] = 0.f; }

    int sd = tid & 15, sa = tid >> 4;
    int kb = ((sa & 1) << 3) | (((sa >> 1) & 1) << 2) | ((sa >> 2) << 4);

    short4v vpack[4];
    #pragma unroll
    for (int cc = 0; cc < 4; ++cc) {
        const short* vp = Vh + (size_t)(cc * 64 + kb) * 16 + sd;
        vpack[cc].x = vp[0]; vpack[cc].y = vp[16];
        vpack[cc].z = vp[32]; vpack[cc].w = vp[48];
    }

    short8 kf1 = *(const short8*)(Kh + (size_t)m * 16 + hi * 8);
    short8 kf2 = *(const short8*)(Kh + (size_t)(32 + m) * 16 + hi * 8);

    for (int sc = 0; sc < N; sc += 256) {
        __syncthreads();
        #pragma unroll
        for (int cc = 0; cc < 4; ++cc)
            *(short4v*)(&Vt[sd][cc * 64 + sa * 4]) = vpack[cc];
        if (sc + 256 < N) {
            #pragma unroll
            for (int cc = 0; cc < 4; ++cc) {
                const short* vp = Vh + (size_t)(sc + 256 + cc * 64 + kb) * 16 + sd;
                vpack[cc].x = vp[0]; vpack[cc].y = vp[16];
                vpack[cc].z = vp[32]; vpack[cc].w = vp[48];
            }
        }
        __syncthreads();

        #pragma unroll
        for (int it = 0; it < 4; ++it) {
            int c = sc + it * 64;
            int cn = (c + 64) & (N - 1);

            float16v S1 = __builtin_amdgcn_mfma_f32_32x32x16_bf16(kf1, qf, zf, 0, 0, 0);
            float16v S2 = __builtin_amdgcn_mfma_f32_32x32x16_bf16(kf2, qf, zf, 0, 0, 0);

            kf1 = *(const short8*)(Kh + (size_t)(cn + m) * 16 + hi * 8);
            kf2 = *(const short8*)(Kh + (size_t)(cn + 32 + m) * 16 + hi * 8);

            // exp+pack+PV interleaved per p-block: only 4 pack dwords live at
            // once (was 16).  Mapping identical to r15: p0=S1[0..7], p1=S1[8..15],
            // p2=S2[0..7], p3=S2[8..15]; vf = Vt[m][it*64 + p*16 + hi*8].
            union { uint4v u; short8 s; } pk;
            short8 vf;

            pk.u = (uint4v){
                cvt_pk2(__builtin_amdgcn_exp2f(S1[0]), __builtin_amdgcn_exp2f(S1[1])),
                cvt_pk2(__builtin_amdgcn_exp2f(S1[2]), __builtin_amdgcn_exp2f(S1[3])),
                cvt_pk2(__builtin_amdgcn_exp2f(S1[4]), __builtin_amdgcn_exp2f(S1[5])),
                cvt_pk2(__builtin_amdgcn_exp2f(S1[6]), __builtin_amdgcn_exp2f(S1[7]))};
            vf = *(short8*)(&Vt[m][it * 64 + 0 * 16 + hi * 8]);
            Oacc = __builtin_amdgcn_mfma_f32_32x32x16_bf16(vf, pk.s, Oacc, 0, 0, 0);

            pk.u = (uint4v){
                cvt_pk2(__builtin_amdgcn_exp2f(S1[8]),  __builtin_amdgcn_exp2f(S1[9])),
                cvt_pk2(__builtin_amdgcn_exp2f(S1[10]), __builtin_amdgcn_exp2f(S1[11])),
                cvt_pk2(__builtin_amdgcn_exp2f(S1[12]), __builtin_amdgcn_exp2f(S1[13])),
                cvt_pk2(__builtin_amdgcn_exp2f(S1[14]), __builtin_amdgcn_exp2f(S1[15]))};
            vf = *(short8*)(&Vt[m][it * 64 + 1 * 16 + hi * 8]);
            Oacc = __builtin_amdgcn_mfma_f32_32x32x16_bf16(vf, pk.s, Oacc, 0, 0, 0);

            pk.u = (uint4v){
                cvt_pk2(__builtin_amdgcn_exp2f(S2[0]), __builtin_amdgcn_exp2f(S2[1])),
                cvt_pk2(__builtin_amdgcn_exp2f(S2[2]), __builtin_amdgcn_exp2f(S2[3])),
                cvt_pk2(__builtin_amdgcn_exp2f(S2[4]), __builtin_amdgcn_exp2f(S2[5])),
                cvt_pk2(__builtin_amdgcn_exp2f(S2[6]), __builtin_amdgcn_exp2f(S2[7]))};
            vf = *(short8*)(&Vt[m][it * 64 + 2 * 16 + hi * 8]);
            Oacc = __builtin_amdgcn_mfma_f32_32x32x16_bf16(vf, pk.s, Oacc, 0, 0, 0);

            pk.u = (uint4v){
                cvt_pk2(__builtin_amdgcn_exp2f(S2[8]),  __builtin_amdgcn_exp2f(S2[9])),
                cvt_pk2(__builtin_amdgcn_exp2f(S2[10]), __builtin_amdgcn_exp2f(S2[11])),
                cvt_pk2(__builtin_amdgcn_exp2f(S2[12]), __builtin_amdgcn_exp2f(S2[13])),
                cvt_pk2(__builtin_amdgcn_exp2f(S2[14]), __builtin_amdgcn_exp2f(S2[15]))};
            vf = *(short8*)(&Vt[m][it * 64 + 3 * 16 + hi * 8]);
            Oacc = __builtin_amdgcn_mfma_f32_32x32x16_bf16(vf, pk.s, Oacc, 0, 0, 0);
        }
    }

    float Lq = __shfl(Oacc[8], m, 64);
    float inv = 1.0f / Lq;
    uint32_t o0 = cvt_pk2(Oacc[0] * inv, Oacc[1] * inv);
    uint32_t o1 = cvt_pk2(Oacc[2] * inv, Oacc[3] * inv);
    uint32_t o2 = cvt_pk2(Oacc[4] * inv, Oacc[5] * inv);
    uint32_t o3 = cvt_pk2(Oacc[6] * inv, Oacc[7] * inv);
    short* row = Out + ((size_t)(b * 2048 + qbase + m)) * 256 + h * 16;
    uint2 w0; w0.x = o0; w0.y = o1;
    uint2 w1; w1.x = o2; w1.y = o3;
    *(uint2*)(row + hi * 4) = w0;
    *(uint2*)(row + 8 + hi * 4) = w1;
}

// ---------------- launcher ----------------

extern "C" void kernel_launch(void* const* d_in, const int* in_sizes, int n_in,
                              void* d_out, int out_size, void* d_ws, size_t ws_size,
                              hipStream_t stream) {
    const float* x      = (const float*)d_in[0];
    const float* w_qkv  = (const float*)d_in[1];
    const float* b_qkv  = (const float*)d_in[2];
    const float* w_proj = (const float*)d_in[3];
    const float* b_proj = (const float*)d_in[4];
    float* out = (float*)d_out;

    short* wqkvT  = (short*)d_ws;          // 768*256
    short* wprojT = wqkvT + 196608;        // 256*256
    short* Qb     = wprojT + 65536;        // (B*H, N, D) bf16
    short* Kb     = Qb + 2097152;
    short* Vb     = Kb + 2097152;
    short* Ab     = Vb + 2097152;          // attention output (B,N,C) bf16

    cvtW_kernel<<<64, 256, 0, stream>>>(w_qkv, w_proj, wqkvT, wprojT);

    gemm_kernel<0><<<dim3(128, 12), 256, 0, stream>>>(x, wqkvT, b_qkv, Qb, Kb, Vb, nullptr);

    attn_kernel<<<dim3(16, 64), 256, 0, stream>>>(Qb, Kb, Vb, Ab);

    gemm_kernel<1><<<dim3(128, 4), 256, 0, stream>>>(Ab, wprojT, b_proj,
                                                     nullptr, nullptr, nullptr, out);
}

// Round 7
// 126.872 us; speedup vs baseline: 1.3896x; 1.0137x over previous
//
#include <hip/hip_runtime.h>
#include <stdint.h>

typedef __attribute__((ext_vector_type(8))) short short8;
typedef __attribute__((ext_vector_type(4))) short short4v;
typedef __attribute__((ext_vector_type(4))) float float4v;
typedef __attribute__((ext_vector_type(16))) float float16v;
typedef __attribute__((ext_vector_type(4))) uint32_t uint4v;

__device__ __forceinline__ short f2bf(float f) {
    union { float f; uint32_t u; } v; v.f = f;
    uint32_t u = v.u;
    uint32_t r = (u + 0x7fffu + ((u >> 16) & 1u)) >> 16;
    return (short)r;
}

#if __has_builtin(__builtin_amdgcn_cvt_pk_bf16_f32)
typedef __bf16 bf16x2_t __attribute__((ext_vector_type(2)));
__device__ __forceinline__ uint32_t cvt_pk2(float a, float b) {
    union { bf16x2_t v; uint32_t u; } c;
    c.v = __builtin_amdgcn_cvt_pk_bf16_f32(a, b);
    return c.u;
}
#else
__device__ __forceinline__ uint32_t cvt_pk2(float a, float b) {
    union { float f; uint32_t u; } x, y; x.f = a; y.f = b;
    return ((x.u + 0x8000u) >> 16) | ((y.u + 0x8000u) & 0xFFFF0000u);
}
#endif

// ---------------- coalesced weight transpose-convert (r16) ----------------

__global__ __launch_bounds__(256) void cvtW_kernel(const float* __restrict__ wqkv,
                                                   const float* __restrict__ wproj,
                                                   short* __restrict__ outq,
                                                   short* __restrict__ outp) {
    __shared__ short T[64][66];
    int t = blockIdx.x;
    const float* src; short* dst; int srcld, k0, n0;
    if (t < 48) {
        k0 = (t & 3) * 64; n0 = (t >> 2) * 64;
        src = wqkv; srcld = 768; dst = outq;
    } else {
        int i = t - 48;
        k0 = (i & 3) * 64; n0 = (i >> 2) * 64;
        src = wproj; srcld = 256; dst = outp;
    }
    int row = threadIdx.x >> 2, seg = threadIdx.x & 3;
    const float* s = src + (size_t)(k0 + row) * srcld + n0 + seg * 16;
    float4 f0 = *(const float4*)s;
    float4 f1 = *(const float4*)(s + 4);
    float4 f2 = *(const float4*)(s + 8);
    float4 f3 = *(const float4*)(s + 12);
    uint32_t* tw = (uint32_t*)&T[row][seg * 16];
    tw[0] = cvt_pk2(f0.x, f0.y); tw[1] = cvt_pk2(f0.z, f0.w);
    tw[2] = cvt_pk2(f1.x, f1.y); tw[3] = cvt_pk2(f1.z, f1.w);
    tw[4] = cvt_pk2(f2.x, f2.y); tw[5] = cvt_pk2(f2.z, f2.w);
    tw[6] = cvt_pk2(f3.x, f3.y); tw[7] = cvt_pk2(f3.z, f3.w);
    __syncthreads();
    short tmp[16] __attribute__((aligned(16)));
    #pragma unroll
    for (int j = 0; j < 16; ++j) tmp[j] = T[seg * 16 + j][row];
    short* d = dst + (size_t)(n0 + row) * 256 + k0 + seg * 16;
    *(short8*)d       = *(short8*)&tmp[0];
    *(short8*)(d + 8) = *(short8*)&tmp[8];
}

// ---------------- GEMM (r5 structure — best measured): 64x64 tile ----------------
// Three GEMM variants measured (r5 / gemm2+xb / gemm2): non-attn block is
// insensitive within ±3us at this K=256 shape.  Frozen on r5.

template<int MODE>
__global__ __launch_bounds__(256) void gemm_kernel(
    const void* __restrict__ Ap, const short* __restrict__ Bt,
    const float* __restrict__ bias,
    short* __restrict__ outQ, short* __restrict__ outK, short* __restrict__ outV,
    float* __restrict__ outP)
{
    const int K = 256;
    int m0 = blockIdx.x * 64;
    int n0 = blockIdx.y * 64;
    int tid = threadIdx.x;
    int wave = tid >> 6, lane = tid & 63, quad = lane >> 4, lc = lane & 15;

    __shared__ __align__(16) short As[64 * 48];
    __shared__ __align__(16) short Bs[64 * 48];

    float4v acc[4];
    #pragma unroll
    for (int t = 0; t < 4; ++t) acc[t] = (float4v){0.f, 0.f, 0.f, 0.f};

    int srow = tid >> 2, sseg = tid & 3;

    for (int c = 0; c < K; c += 32) {
        __syncthreads();
        if (MODE == 0) {
            const float* src = (const float*)Ap + (size_t)(m0 + srow) * K + c + sseg * 8;
            float4 f0 = *(const float4*)src;
            float4 f1 = *(const float4*)(src + 4);
            uint4v u; u.x = cvt_pk2(f0.x, f0.y); u.y = cvt_pk2(f0.z, f0.w);
            u.z = cvt_pk2(f1.x, f1.y); u.w = cvt_pk2(f1.z, f1.w);
            *(uint4v*)(&As[srow * 48 + sseg * 8]) = u;
        } else {
            *(short8*)(&As[srow * 48 + sseg * 8]) =
                *(const short8*)((const short*)Ap + (size_t)(m0 + srow) * K + c + sseg * 8);
        }
        *(short8*)(&Bs[srow * 48 + sseg * 8]) =
            *(const short8*)(Bt + (size_t)(n0 + srow) * K + c + sseg * 8);
        __syncthreads();

        short8 af = *(short8*)(&As[(wave * 16 + lc) * 48 + quad * 8]);
        #pragma unroll
        for (int t = 0; t < 4; ++t) {
            short8 bf = *(short8*)(&Bs[(t * 16 + lc) * 48 + quad * 8]);
            acc[t] = __builtin_amdgcn_mfma_f32_16x16x32_bf16(af, bf, acc[t], 0, 0, 0);
        }
    }

    #pragma unroll
    for (int t = 0; t < 4; ++t) {
        int cg = n0 + t * 16 + lc;
        float bv = bias[cg];
        #pragma unroll
        for (int r = 0; r < 4; ++r) {
            int rg = m0 + wave * 16 + quad * 4 + r;
            float val = acc[t][r] + bv;
            if (MODE == 0) {
                int sq = cg >> 8, rem = cg & 255, h = rem >> 4, d = rem & 15;
                int b = rg >> 11, n = rg & 2047;
                if (sq == 0) val *= 1.4426950408889634f;  // fold log2(e) into Q
                short* dst = (sq == 0) ? outQ : ((sq == 1) ? outK : outV);
                dst[((((size_t)b * 16 + h) * 2048 + n) << 4) + d] = f2bf(val);
            } else {
                outP[(size_t)rg * 256 + cg] = val;
            }
        }
    }
}

// ---------------- flash attention (r18: S-serialized, zero-C literal) ------------
// R6 post-mortem: interleaving bought -6.4us via ILP, but occupancy stayed
// 2.3 waves/SIMD — register hypothesis not yet falsified because S1+S2 (32) and
// zf (16 held zeros) remained live.  r18 removes both:
//   * literal-zero C operand -> backend can fold MFMA src2 to inline 0 (-16)
//   * S2's MFMA issued only AFTER S1 fully consumed -> peak S-liveness 16 (-16)
// launch_bounds(256,3) kept (cap 170; HW runs 4 waves if usage <=128).
// Pre-committed null read: occupancy flat + dur >=51us -> register lever dead,
// kernel is latency-structure-bound; stop attn surgery.

__global__ __launch_bounds__(256, 3) void attn_kernel(
    const short* __restrict__ Q, const short* __restrict__ Kp, const short* __restrict__ V,
    short* __restrict__ Out)
{
    const int N = 2048;
    int bh = blockIdx.y;
    int b = bh >> 4, h = bh & 15;
    int tid = threadIdx.x;
    int wave = tid >> 6, lane = tid & 63;
    int m = lane & 31, hi = lane >> 5;
    int qbase = blockIdx.x * 128 + wave * 32;

    const short* Qh = Q + (size_t)bh * N * 16;
    const short* Kh = Kp + (size_t)bh * N * 16;
    const short* Vh = V + (size_t)bh * N * 16;

    __shared__ __align__(16) short Vt[32][264];

    for (int idx = tid; idx < 16 * 264; idx += 256) {
        int row = 16 + idx / 264;
        int col = idx - (row - 16) * 264;
        Vt[row][col] = (row == 16) ? (short)0x3F80 : (short)0;
    }

    short8 qf = *(const short8*)(Qh + (size_t)(qbase + m) * 16 + hi * 8);

    float16v Oacc;
    #pragma unroll
    for (int j = 0; j < 16; ++j) Oacc[j] = 0.f;

    const float16v ZF = (float16v)(0.0f);   // literal zero C — foldable to inline 0

    int sd = tid & 15, sa = tid >> 4;
    int kb = ((sa & 1) << 3) | (((sa >> 1) & 1) << 2) | ((sa >> 2) << 4);

    short4v vpack[4];
    #pragma unroll
    for (int cc = 0; cc < 4; ++cc) {
        const short* vp = Vh + (size_t)(cc * 64 + kb) * 16 + sd;
        vpack[cc].x = vp[0]; vpack[cc].y = vp[16];
        vpack[cc].z = vp[32]; vpack[cc].w = vp[48];
    }

    short8 kf1 = *(const short8*)(Kh + (size_t)m * 16 + hi * 8);
    short8 kf2 = *(const short8*)(Kh + (size_t)(32 + m) * 16 + hi * 8);

    for (int sc = 0; sc < N; sc += 256) {
        __syncthreads();
        #pragma unroll
        for (int cc = 0; cc < 4; ++cc)
            *(short4v*)(&Vt[sd][cc * 64 + sa * 4]) = vpack[cc];
        if (sc + 256 < N) {
            #pragma unroll
            for (int cc = 0; cc < 4; ++cc) {
                const short* vp = Vh + (size_t)(sc + 256 + cc * 64 + kb) * 16 + sd;
                vpack[cc].x = vp[0]; vpack[cc].y = vp[16];
                vpack[cc].z = vp[32]; vpack[cc].w = vp[48];
            }
        }
        __syncthreads();

        #pragma unroll
        for (int it = 0; it < 4; ++it) {
            int c = sc + it * 64;
            int cn = (c + 64) & (N - 1);

            union { uint4v u; short8 s; } pk;
            short8 vf;

            // ---- first 32 keys: S = kf1 * qf ----
            float16v S = __builtin_amdgcn_mfma_f32_32x32x16_bf16(kf1, qf, ZF, 0, 0, 0);
            kf1 = *(const short8*)(Kh + (size_t)(cn + m) * 16 + hi * 8);

            pk.u = (uint4v){
                cvt_pk2(__builtin_amdgcn_exp2f(S[0]), __builtin_amdgcn_exp2f(S[1])),
                cvt_pk2(__builtin_amdgcn_exp2f(S[2]), __builtin_amdgcn_exp2f(S[3])),
                cvt_pk2(__builtin_amdgcn_exp2f(S[4]), __builtin_amdgcn_exp2f(S[5])),
                cvt_pk2(__builtin_amdgcn_exp2f(S[6]), __builtin_amdgcn_exp2f(S[7]))};
            vf = *(short8*)(&Vt[m][it * 64 + 0 * 16 + hi * 8]);
            Oacc = __builtin_amdgcn_mfma_f32_32x32x16_bf16(vf, pk.s, Oacc, 0, 0, 0);

            pk.u = (uint4v){
                cvt_pk2(__builtin_amdgcn_exp2f(S[8]),  __builtin_amdgcn_exp2f(S[9])),
                cvt_pk2(__builtin_amdgcn_exp2f(S[10]), __builtin_amdgcn_exp2f(S[11])),
                cvt_pk2(__builtin_amdgcn_exp2f(S[12]), __builtin_amdgcn_exp2f(S[13])),
                cvt_pk2(__builtin_amdgcn_exp2f(S[14]), __builtin_amdgcn_exp2f(S[15]))};
            vf = *(short8*)(&Vt[m][it * 64 + 1 * 16 + hi * 8]);
            Oacc = __builtin_amdgcn_mfma_f32_32x32x16_bf16(vf, pk.s, Oacc, 0, 0, 0);

            // ---- second 32 keys: S reused (peak S-liveness stays 16) ----
            S = __builtin_amdgcn_mfma_f32_32x32x16_bf16(kf2, qf, ZF, 0, 0, 0);
            kf2 = *(const short8*)(Kh + (size_t)(cn + 32 + m) * 16 + hi * 8);

            pk.u = (uint4v){
                cvt_pk2(__builtin_amdgcn_exp2f(S[0]), __builtin_amdgcn_exp2f(S[1])),
                cvt_pk2(__builtin_amdgcn_exp2f(S[2]), __builtin_amdgcn_exp2f(S[3])),
                cvt_pk2(__builtin_amdgcn_exp2f(S[4]), __builtin_amdgcn_exp2f(S[5])),
                cvt_pk2(__builtin_amdgcn_exp2f(S[6]), __builtin_amdgcn_exp2f(S[7]))};
            vf = *(short8*)(&Vt[m][it * 64 + 2 * 16 + hi * 8]);
            Oacc = __builtin_amdgcn_mfma_f32_32x32x16_bf16(vf, pk.s, Oacc, 0, 0, 0);

            pk.u = (uint4v){
                cvt_pk2(__builtin_amdgcn_exp2f(S[8]),  __builtin_amdgcn_exp2f(S[9])),
                cvt_pk2(__builtin_amdgcn_exp2f(S[10]), __builtin_amdgcn_exp2f(S[11])),
                cvt_pk2(__builtin_amdgcn_exp2f(S[12]), __builtin_amdgcn_exp2f(S[13])),
                cvt_pk2(__builtin_amdgcn_exp2f(S[14]), __builtin_amdgcn_exp2f(S[15]))};
            vf = *(short8*)(&Vt[m][it * 64 + 3 * 16 + hi * 8]);
            Oacc = __builtin_amdgcn_mfma_f32_32x32x16_bf16(vf, pk.s, Oacc, 0, 0, 0);
        }
    }

    float Lq = __shfl(Oacc[8], m, 64);
    float inv = 1.0f / Lq;
    uint32_t o0 = cvt_pk2(Oacc[0] * inv, Oacc[1] * inv);
    uint32_t o1 = cvt_pk2(Oacc[2] * inv, Oacc[3] * inv);
    uint32_t o2 = cvt_pk2(Oacc[4] * inv, Oacc[5] * inv);
    uint32_t o3 = cvt_pk2(Oacc[6] * inv, Oacc[7] * inv);
    short* row = Out + ((size_t)(b * 2048 + qbase + m)) * 256 + h * 16;
    uint2 w0; w0.x = o0; w0.y = o1;
    uint2 w1; w1.x = o2; w1.y = o3;
    *(uint2*)(row + hi * 4) = w0;
    *(uint2*)(row + 8 + hi * 4) = w1;
}

// ---------------- launcher ----------------

extern "C" void kernel_launch(void* const* d_in, const int* in_sizes, int n_in,
                              void* d_out, int out_size, void* d_ws, size_t ws_size,
                              hipStream_t stream) {
    const float* x      = (const float*)d_in[0];
    const float* w_qkv  = (const float*)d_in[1];
    const float* b_qkv  = (const float*)d_in[2];
    const float* w_proj = (const float*)d_in[3];
    const float* b_proj = (const float*)d_in[4];
    float* out = (float*)d_out;

    short* wqkvT  = (short*)d_ws;          // 768*256
    short* wprojT = wqkvT + 196608;        // 256*256
    short* Qb     = wprojT + 65536;        // (B*H, N, D) bf16
    short* Kb     = Qb + 2097152;
    short* Vb     = Kb + 2097152;
    short* Ab     = Vb + 2097152;          // attention output (B,N,C) bf16

    cvtW_kernel<<<64, 256, 0, stream>>>(w_qkv, w_proj, wqkvT, wprojT);

    gemm_kernel<0><<<dim3(128, 12), 256, 0, stream>>>(x, wqkvT, b_qkv, Qb, Kb, Vb, nullptr);

    attn_kernel<<<dim3(16, 64), 256, 0, stream>>>(Qb, Kb, Vb, Ab);

    gemm_kernel<1><<<dim3(128, 4), 256, 0, stream>>>(Ab, wprojT, b_proj,
                                                     nullptr, nullptr, nullptr, out);
}